// Round 16
// baseline (358.786 us; speedup 1.0000x reference)
//
#include <hip/hip_runtime.h>
#include <hip/hip_fp16.h>
#include <math.h>

#define N_NODES 100000
#define N_EDGES 1600000
#define IN_FEATS 128
#define H_FEATS 64
#define SCAN_BLOCKS 391   // ceil(100000/256)
#define NB_HIST 1024
#define NB_TRUNK 1563     // trunk tiles (64 rows each)
#define NB_WPACK 64
// mega1 grid: [0,2048) even->hist, odd->trunk; [2048,2587) trunk; [2587,2651) wpack
#define NB_MEGA1 (NB_HIST + NB_TRUNK + NB_WPACK)

typedef _Float16 f16x8 __attribute__((ext_vector_type(8)));
typedef float f32x4 __attribute__((ext_vector_type(4)));

// ---------------- mega1: hist + trunk + wpack co-scheduled ----------------
// hist (atomic-latency-bound, 1.6M atomicAdd, VALU ~0%) interleaves 1:1 with
// trunk (VALU/LDS-bound) so trunk's FMAs run in hist's atomic-wait bubbles.
// All three roles are mutually independent (hist: dst only; trunk: X/W only;
// wpack: thetas/Wm1 only) and all precede the scan -> fill chain.
__global__ __launch_bounds__(256) void mega1_kernel(
    // hist
    const int* __restrict__ dst, int* __restrict__ degi,
    // trunk
    const float* __restrict__ X, const float* __restrict__ W1, const float* __restrict__ b1,
    const float* __restrict__ W2, const float* __restrict__ b2, __half* __restrict__ H,
    // wpack
    const float* __restrict__ thetas, const float* __restrict__ Wm1,
    __half* __restrict__ Bpack)
{
    int b = blockIdx.x;
    int t = threadIdx.x;

    bool is_trunk = (b < 2 * NB_HIST) ? ((b & 1) == 1) : (b < 2 * NB_HIST + (NB_TRUNK - NB_HIST));
    if (is_trunk) {
        int tb = (b < 2 * NB_HIST) ? (b >> 1) : (NB_HIST + (b - 2 * NB_HIST));
        __shared__ float stage[16][IN_FEATS];   // 8 KB
        __shared__ float part[4][16][64];       // 16 KB
        __shared__ float h1s[16][64];           // 4 KB
        int wv = __builtin_amdgcn_readfirstlane(t >> 6);
        int lane = t & 63;
        float w1r[32], w2r[16];
        #pragma unroll
        for (int i = 0; i < 32; ++i) w1r[i] = W1[(wv * 32 + i) * 64 + lane];
        #pragma unroll
        for (int i = 0; i < 16; ++i) w2r[i] = W2[(wv * 16 + i) * 64 + lane];
        float b1v = b1[lane], b2v = b2[lane];
        int srow = t >> 5, sf4 = t & 31;
        float4* st4 = (float4*)stage;

        for (int batch = 0; batch < 4; ++batch) {
            int row0 = tb * 64 + batch * 16;
            #pragma unroll
            for (int p = 0; p < 2; ++p) {
                int row = row0 + srow + 8 * p;
                if (row >= N_NODES) row = N_NODES - 1;
                st4[t + 256 * p] =
                    ((const float4*)(X + (size_t)row * IN_FEATS))[sf4];
            }
            __syncthreads();
            float acc[16];
            #pragma unroll
            for (int r = 0; r < 16; ++r) {
                const float4* xb = (const float4*)&stage[r][wv * 32];
                float a = 0.f, bb = 0.f;
                #pragma unroll
                for (int i4 = 0; i4 < 8; i4 += 2) {
                    float4 v0 = xb[i4], v1 = xb[i4 + 1];
                    a = fmaf(v0.x, w1r[i4 * 4 + 0], a);
                    a = fmaf(v0.y, w1r[i4 * 4 + 1], a);
                    a = fmaf(v0.z, w1r[i4 * 4 + 2], a);
                    a = fmaf(v0.w, w1r[i4 * 4 + 3], a);
                    bb = fmaf(v1.x, w1r[i4 * 4 + 4], bb);
                    bb = fmaf(v1.y, w1r[i4 * 4 + 5], bb);
                    bb = fmaf(v1.z, w1r[i4 * 4 + 6], bb);
                    bb = fmaf(v1.w, w1r[i4 * 4 + 7], bb);
                }
                acc[r] = a + bb;
            }
            #pragma unroll
            for (int r = 0; r < 16; ++r) part[wv][r][lane] = acc[r];
            __syncthreads();
            #pragma unroll
            for (int rr = 0; rr < 4; ++rr) {
                int r = wv * 4 + rr;
                float y1 = part[0][r][lane] + part[1][r][lane] +
                           part[2][r][lane] + part[3][r][lane] + b1v;
                h1s[r][lane] = fmaxf(y1, 0.f);
            }
            __syncthreads();
            float acc2[16];
            #pragma unroll
            for (int r = 0; r < 16; ++r) {
                const float4* xb = (const float4*)&h1s[r][wv * 16];
                float a = 0.f, bb = 0.f;
                #pragma unroll
                for (int i4 = 0; i4 < 4; i4 += 2) {
                    float4 v0 = xb[i4], v1 = xb[i4 + 1];
                    a = fmaf(v0.x, w2r[i4 * 4 + 0], a);
                    a = fmaf(v0.y, w2r[i4 * 4 + 1], a);
                    a = fmaf(v0.z, w2r[i4 * 4 + 2], a);
                    a = fmaf(v0.w, w2r[i4 * 4 + 3], a);
                    bb = fmaf(v1.x, w2r[i4 * 4 + 4], bb);
                    bb = fmaf(v1.y, w2r[i4 * 4 + 5], bb);
                    bb = fmaf(v1.z, w2r[i4 * 4 + 6], bb);
                    bb = fmaf(v1.w, w2r[i4 * 4 + 7], bb);
                }
                acc2[r] = a + bb;
            }
            __syncthreads();
            #pragma unroll
            for (int r = 0; r < 16; ++r) part[wv][r][lane] = acc2[r];
            __syncthreads();
            #pragma unroll
            for (int rr = 0; rr < 4; ++rr) {
                int r = wv * 4 + rr;
                int row = row0 + r;
                float y2 = part[0][r][lane] + part[1][r][lane] +
                           part[2][r][lane] + part[3][r][lane] + b2v;
                if (row < N_NODES) H[(size_t)row * 64 + lane] = __float2half(fmaxf(y2, 0.f));
            }
            __syncthreads();
        }
        return;
    }

    if (b < 2 * NB_HIST + (NB_TRUNK - NB_HIST)) {
        // hist role (b even, b < 2048): id in [0, NB_HIST)
        int hid = b >> 1;
        int tid = hid * 256 + t;
        const int stride = NB_HIST * 256;
        for (int e = tid; e < N_EDGES; e += stride)
            atomicAdd(&degi[dst[e]], 1);
        return;
    }

    // wpack role: Weff collapsed + fp16 + MFMA B-fragment order
    // Fragment (s,nt): lane l, elem j holds B[k=32s+(l>>4)*8+j][n=nt*16+(l&15)]
    {
        int wb = b - (2 * NB_HIST + (NB_TRUNK - NB_HIST));
        int u = wb * 256 + t;   // 16384 total
        int j = u & 7, lane = (u >> 3) & 63, frag = u >> 9;
        int nt = frag & 3, s = frag >> 2;
        int k = 32 * s + ((lane >> 4) << 3) + j;
        int q = k >> 6, f = k & 63;
        int n = nt * 16 + (lane & 15);
        float acc = 0.f;
        #pragma unroll
        for (int c = 0; c < 3; ++c)
            acc = fmaf(thetas[c * 4 + q], Wm1[(c * 64 + f) * 64 + n], acc);
        Bpack[u] = __float2half(acc);
    }
}

// ---------------- scan1: block-local exclusive scan of degi + dinv fold ----------------
__global__ __launch_bounds__(256) void scan1_kernel(const int* __restrict__ degi,
                                                    int* __restrict__ rowp,
                                                    int* __restrict__ bsums,
                                                    float* __restrict__ dinv) {
    __shared__ int tmp[256];
    int i = blockIdx.x * 256 + threadIdx.x;
    int v = (i < N_NODES) ? degi[i] : 0;
    tmp[threadIdx.x] = v;
    __syncthreads();
    #pragma unroll
    for (int off = 1; off < 256; off <<= 1) {
        int t = (threadIdx.x >= off) ? tmp[threadIdx.x - off] : 0;
        __syncthreads();
        tmp[threadIdx.x] += t;
        __syncthreads();
    }
    if (i < N_NODES) {
        rowp[i] = tmp[threadIdx.x] - v;
        dinv[i] = rsqrtf(fmaxf((float)v, 1.0f));
    }
    if (threadIdx.x == 255) bsums[blockIdx.x] = tmp[255];
}

__global__ __launch_bounds__(512) void scan2_kernel(int* __restrict__ bsums) {
    __shared__ int tmp[512];
    int t = threadIdx.x;
    int v = (t < SCAN_BLOCKS) ? bsums[t] : 0;
    tmp[t] = v;
    __syncthreads();
    #pragma unroll
    for (int off = 1; off < 512; off <<= 1) {
        int x = (t >= off) ? tmp[t - off] : 0;
        __syncthreads();
        tmp[t] += x;
        __syncthreads();
    }
    if (t < SCAN_BLOCKS) bsums[t] = tmp[t] - v;
}

__global__ __launch_bounds__(256) void scan3_kernel(int* __restrict__ rowp,
                                                    const int* __restrict__ bsums) {
    int i = blockIdx.x * 256 + threadIdx.x;
    if (i < N_NODES) rowp[i] += bsums[blockIdx.x];
    if (i == N_NODES) rowp[N_NODES] = N_EDGES;
}

// ---------------- fill CSR slots: single packed 8B write per edge (solo launch) ----
__global__ __launch_bounds__(256) void fill_kernel(const int* __restrict__ src,
                                                   const int* __restrict__ dst,
                                                   const int* __restrict__ rowp,
                                                   const float* __restrict__ dinv,
                                                   int* __restrict__ cursor,
                                                   int2* __restrict__ epack) {
    int tid = blockIdx.x * 256 + threadIdx.x;
    int stride = gridDim.x * 256;
    for (int e = tid; e < N_EDGES; e += stride) {
        int d = dst[e];
        int s = src[e];
        int slot = rowp[d] + atomicAdd(&cursor[d], 1);
        epack[slot] = make_int2(s, __float_as_int(dinv[s]));
    }
}

// ---------------- gather pass: Fnew[n] = Fprev[n] - dinv[n]*sum_e w_e*Fprev[s_e]
// half tables (128B row per edge), fp32 accumulate; one wave per node.
__global__ __launch_bounds__(256) void gather_kernel(
    const __half* __restrict__ Fprev, const int* __restrict__ rowp,
    const int2* __restrict__ epack, const float* __restrict__ dinv,
    __half* __restrict__ Fnew)
{
    int wv = __builtin_amdgcn_readfirstlane(threadIdx.x >> 6);
    int wid = blockIdx.x * 4 + wv;   // node id (uniform)
    int lane = threadIdx.x & 63;
    int beg = rowp[wid], end = rowp[wid + 1];
    float acc = 0.0f;
    int j = beg;
    for (; j + 7 < end; j += 8) {
        int2 e0 = epack[j],     e1 = epack[j + 1], e2 = epack[j + 2], e3 = epack[j + 3];
        int2 e4 = epack[j + 4], e5 = epack[j + 5], e6 = epack[j + 6], e7 = epack[j + 7];
        float v0 = __half2float(Fprev[(size_t)e0.x * 64 + lane]);
        float v1 = __half2float(Fprev[(size_t)e1.x * 64 + lane]);
        float v2 = __half2float(Fprev[(size_t)e2.x * 64 + lane]);
        float v3 = __half2float(Fprev[(size_t)e3.x * 64 + lane]);
        float v4 = __half2float(Fprev[(size_t)e4.x * 64 + lane]);
        float v5 = __half2float(Fprev[(size_t)e5.x * 64 + lane]);
        float v6 = __half2float(Fprev[(size_t)e6.x * 64 + lane]);
        float v7 = __half2float(Fprev[(size_t)e7.x * 64 + lane]);
        acc = fmaf(v0, __int_as_float(e0.y), acc);
        acc = fmaf(v1, __int_as_float(e1.y), acc);
        acc = fmaf(v2, __int_as_float(e2.y), acc);
        acc = fmaf(v3, __int_as_float(e3.y), acc);
        acc = fmaf(v4, __int_as_float(e4.y), acc);
        acc = fmaf(v5, __int_as_float(e5.y), acc);
        acc = fmaf(v6, __int_as_float(e6.y), acc);
        acc = fmaf(v7, __int_as_float(e7.y), acc);
    }
    for (; j < end; ++j) {
        int2 e = epack[j];
        acc = fmaf(__half2float(Fprev[(size_t)e.x * 64 + lane]), __int_as_float(e.y), acc);
    }
    float self = __half2float(Fprev[(size_t)wid * 64 + lane]);
    Fnew[(size_t)wid * 64 + lane] = __float2half(self - acc * dinv[wid]);
}

// ---------------- final (MFMA): out = relu(A@B + bm1) @ Wm2 + bm2 ----------------
// A[100000 x 256] fp16 = [L0|L1|L2|L3] column-blocked (Lh contiguous);
// B[256 x 64] fp16 pre-packed in fragment order (Bpack).
// D: col n = nt*16 + (l&15), row = row0 + (l>>4)*4 + reg   [m89 layout]
__global__ __launch_bounds__(256) void final_mfma_kernel(
    const __half* __restrict__ L0h, const __half* __restrict__ Bpack,
    const float* __restrict__ Wm2, const float* __restrict__ bm1,
    const float* __restrict__ bm2, float* __restrict__ out)
{
    const size_t NH = (size_t)N_NODES * 64;
    int t = threadIdx.x;
    int wv = t >> 6;
    int lane = t & 63;
    int gw = blockIdx.x * 4 + wv;          // 1564 waves

    // preload all 32 B fragments (128 VGPRs)
    const f16x8* bp = (const f16x8*)Bpack;
    f16x8 b[4][8];
    #pragma unroll
    for (int s = 0; s < 8; ++s)
        #pragma unroll
        for (int nt = 0; nt < 4; ++nt)
            b[nt][s] = bp[(s * 4 + nt) * 64 + lane];

    // per-lane head constants: n = nt*16 + (lane&15)
    float bm1v[4], w20[4], w21[4];
    #pragma unroll
    for (int nt = 0; nt < 4; ++nt) {
        int n = nt * 16 + (lane & 15);
        bm1v[nt] = bm1[n];
        w20[nt] = Wm2[n * 2 + 0];
        w21[nt] = Wm2[n * 2 + 1];
    }
    float bm20 = bm2[0], bm21 = bm2[1];

    for (int u = 0; u < 4; ++u) {
        int tile = gw * 4 + u;
        if (tile >= 6250) break;           // 6250 * 16 = 100000 exactly
        int row0 = tile * 16;
        const __half* abase = L0h + (size_t)(row0 + (lane & 15)) * 64 + ((lane >> 4) << 3);
        f16x8 a[8];
        #pragma unroll
        for (int s = 0; s < 8; ++s)
            a[s] = *(const f16x8*)(abase + (size_t)(s >> 1) * NH + 32 * (s & 1));
        f32x4 acc[4];
        #pragma unroll
        for (int nt = 0; nt < 4; ++nt) acc[nt] = (f32x4){0.f, 0.f, 0.f, 0.f};
        #pragma unroll
        for (int s = 0; s < 8; ++s)
            #pragma unroll
            for (int nt = 0; nt < 4; ++nt)
                acc[nt] = __builtin_amdgcn_mfma_f32_16x16x32_f16(a[s], b[nt][s], acc[nt], 0, 0, 0);
        // epilogue: relu + bm1, head GEMV, reduce over n within 16-lane groups
        float o0[4], o1[4];
        #pragma unroll
        for (int reg = 0; reg < 4; ++reg) { o0[reg] = 0.f; o1[reg] = 0.f; }
        #pragma unroll
        for (int nt = 0; nt < 4; ++nt)
            #pragma unroll
            for (int reg = 0; reg < 4; ++reg) {
                float v = fmaxf(acc[nt][reg] + bm1v[nt], 0.f);
                o0[reg] = fmaf(v, w20[nt], o0[reg]);
                o1[reg] = fmaf(v, w21[nt], o1[reg]);
            }
        #pragma unroll
        for (int reg = 0; reg < 4; ++reg) {
            #pragma unroll
            for (int m = 8; m > 0; m >>= 1) {
                o0[reg] += __shfl_xor(o0[reg], m);
                o1[reg] += __shfl_xor(o1[reg], m);
            }
        }
        if ((lane & 15) == 0) {
            int rbase = row0 + (lane >> 4) * 4;
            #pragma unroll
            for (int reg = 0; reg < 4; ++reg) {
                out[(rbase + reg) * 2 + 0] = o0[reg] + bm20;
                out[(rbase + reg) * 2 + 1] = o1[reg] + bm21;
            }
        }
    }
}

extern "C" void kernel_launch(void* const* d_in, const int* in_sizes, int n_in,
                              void* d_out, int out_size, void* d_ws, size_t ws_size,
                              hipStream_t stream)
{
    const float* feature = (const float*)d_in[0];
    const int*   src     = (const int*)d_in[1];
    const int*   dst     = (const int*)d_in[2];
    const float* W1      = (const float*)d_in[3];
    const float* b1      = (const float*)d_in[4];
    const float* W2      = (const float*)d_in[5];
    const float* b2      = (const float*)d_in[6];
    const float* thetas  = (const float*)d_in[7];
    const float* Wm1     = (const float*)d_in[8];
    const float* bm1     = (const float*)d_in[9];
    const float* Wm2     = (const float*)d_in[10];
    const float* bm2     = (const float*)d_in[11];
    float* out = (float*)d_out;

    const size_t NH = (size_t)N_NODES * H_FEATS;   // 6.4M elems
    const int NPAD = 100352;
    float*  dinv   = (float*)d_ws;                  // N
    int*    degi   = (int*)(dinv + NPAD);           // N
    int*    rowp   = degi + NPAD;                   // N+1
    int*    bsums  = rowp + NPAD;                   // 512
    int*    cursor = bsums + 512;                   // N
    int2*   epack  = (int2*)(cursor + NPAD);        // E int2
    __half* Lh     = (__half*)(epack + N_EDGES);    // 4 x NH halfs, contiguous
    __half* Bpack  = Lh + 4 * NH;                   // 16384 halfs (32 KB)
    // total ws use ≈ 66 MB

    hipMemsetAsync(degi,   0, N_NODES * sizeof(int), stream);
    hipMemsetAsync(cursor, 0, N_NODES * sizeof(int), stream);

    // phase 1: hist + trunk + wpack co-scheduled (all mutually independent)
    mega1_kernel<<<NB_MEGA1, 256, 0, stream>>>(
        dst, degi,
        feature, W1, b1, W2, b2, Lh,
        thetas, Wm1, Bpack);

    // phase 2: scans (cheap)
    scan1_kernel<<<SCAN_BLOCKS, 256, 0, stream>>>(degi, rowp, bsums, dinv);
    scan2_kernel<<<1, 512, 0, stream>>>(bsums);
    scan3_kernel<<<SCAN_BLOCKS, 256, 0, stream>>>(rowp, bsums);

    // phase 3: fill solo (full atomic concurrency)
    fill_kernel<<<2048, 256, 0, stream>>>(src, dst, rowp, dinv, cursor, epack);

    // phase 4: 3 gather passes
    for (int k = 1; k <= 3; ++k)
        gather_kernel<<<25000, 256, 0, stream>>>(Lh + (size_t)(k - 1) * NH, rowp, epack,
                                                 dinv, Lh + (size_t)k * NH);

    // phase 5: MFMA final
    final_mfma_kernel<<<391, 256, 0, stream>>>(Lh, Bpack, Wm2, bm1, bm2, out);
}

// Round 17
// 286.217 us; speedup vs baseline: 1.2535x; 1.2535x over previous
//
#include <hip/hip_runtime.h>
#include <hip/hip_fp16.h>
#include <math.h>

#define N_NODES 100000
#define N_EDGES 1600000
#define IN_FEATS 128
#define H_FEATS 64
#define NBUK 500          // buckets
#define BSZ 200           // nodes per bucket (500*200 = 100000)
#define NBA 512           // blocks for count/scatter
#define ACHUNK 3125       // 512*3125 = 1600000 exactly

typedef _Float16 f16x8 __attribute__((ext_vector_type(8)));
typedef float f32x4 __attribute__((ext_vector_type(4)));

// ---------------- A: per-block bucket histogram (LDS atomics only) ----------------
__global__ __launch_bounds__(256) void bucketA_kernel(const int* __restrict__ dst,
                                                      int* __restrict__ blkcnt) {
    __shared__ int cnt[NBUK];
    int t = threadIdx.x;
    for (int i = t; i < NBUK; i += 256) cnt[i] = 0;
    __syncthreads();
    int e0 = blockIdx.x * ACHUNK;
    for (int e = e0 + t; e < e0 + ACHUNK; e += 256)
        atomicAdd(&cnt[dst[e] / BSZ], 1);
    __syncthreads();
    for (int i = t; i < NBUK; i += 256)
        blkcnt[blockIdx.x * NBUK + i] = cnt[i];   // coalesced
}

// ---------------- B1: per-bucket exclusive scan over blocks + totals ----------------
__global__ __launch_bounds__(512) void bucketB1_kernel(const int* __restrict__ blkcnt,
                                                       int* __restrict__ boff,
                                                       int* __restrict__ buktot) {
    __shared__ int tmp[512];
    int b = blockIdx.x;      // bucket
    int t = threadIdx.x;     // block index
    int v = blkcnt[t * NBUK + b];
    tmp[t] = v;
    __syncthreads();
    #pragma unroll
    for (int off = 1; off < 512; off <<= 1) {
        int x = (t >= off) ? tmp[t - off] : 0;
        __syncthreads();
        tmp[t] += x;
        __syncthreads();
    }
    boff[t * NBUK + b] = tmp[t] - v;
    if (t == 511) buktot[b] = tmp[511];
}

// ---------------- B2: exclusive scan of bucket totals ----------------
__global__ __launch_bounds__(512) void bucketB2_kernel(const int* __restrict__ buktot,
                                                       int* __restrict__ bukbase,
                                                       int* __restrict__ rowp) {
    __shared__ int tmp[512];
    int t = threadIdx.x;
    int v = (t < NBUK) ? buktot[t] : 0;
    tmp[t] = v;
    __syncthreads();
    #pragma unroll
    for (int off = 1; off < 512; off <<= 1) {
        int x = (t >= off) ? tmp[t - off] : 0;
        __syncthreads();
        tmp[t] += x;
        __syncthreads();
    }
    if (t < NBUK) bukbase[t] = tmp[t] - v;
    if (t == 0) rowp[N_NODES] = N_EDGES;
}

// ---------------- C: scatter edges into bucket-sorted ebuck ----------------
__global__ __launch_bounds__(256) void bucketC_kernel(const int* __restrict__ src,
                                                      const int* __restrict__ dst,
                                                      const int* __restrict__ boff,
                                                      const int* __restrict__ bukbase,
                                                      int2* __restrict__ ebuck) {
    __shared__ int sbase[NBUK];
    __shared__ int cur[NBUK];
    int t = threadIdx.x;
    for (int i = t; i < NBUK; i += 256) {
        sbase[i] = bukbase[i] + boff[blockIdx.x * NBUK + i];
        cur[i] = 0;
    }
    __syncthreads();
    int e0 = blockIdx.x * ACHUNK;
    for (int e = e0 + t; e < e0 + ACHUNK; e += 256) {
        int d = dst[e];
        int b = d / BSZ;
        int r = atomicAdd(&cur[b], 1);
        ebuck[sbase[b] + r] = make_int2(src[e], d);
    }
}

// ---------------- D: per-bucket fine CSR (all in LDS) ----------------
__global__ __launch_bounds__(256) void bucketD_kernel(const int2* __restrict__ ebuck,
                                                      const int* __restrict__ bukbase,
                                                      const int* __restrict__ buktot,
                                                      int* __restrict__ rowp,
                                                      float* __restrict__ dinv,
                                                      int2* __restrict__ epack) {
    __shared__ int deg[BSZ];
    __shared__ int tmp[256];
    __shared__ int nodeoff[BSZ];
    __shared__ int cur2[BSZ];
    int t = threadIdx.x;
    int buk = blockIdx.x;
    int nlo = buk * BSZ;
    int base = bukbase[buk];
    int cnt = buktot[buk];
    for (int i = t; i < BSZ; i += 256) { deg[i] = 0; cur2[i] = 0; }
    __syncthreads();
    for (int k = t; k < cnt; k += 256)
        atomicAdd(&deg[ebuck[base + k].y - nlo], 1);
    __syncthreads();
    int v = (t < BSZ) ? deg[t] : 0;
    tmp[t] = v;
    __syncthreads();
    #pragma unroll
    for (int off = 1; off < 256; off <<= 1) {
        int x = (t >= off) ? tmp[t - off] : 0;
        __syncthreads();
        tmp[t] += x;
        __syncthreads();
    }
    if (t < BSZ) {
        nodeoff[t] = tmp[t] - v;
        rowp[nlo + t] = base + tmp[t] - v;
        dinv[nlo + t] = rsqrtf(fmaxf((float)v, 1.0f));
    }
    __syncthreads();
    for (int k = t; k < cnt; k += 256) {
        int2 e = ebuck[base + k];
        int ld = e.y - nlo;
        int r = atomicAdd(&cur2[ld], 1);
        epack[base + nodeoff[ld] + r] = make_int2(e.x, 0);
    }
}

// ---------------- E: fill epack.y = bits(dinv[src]) (dinv is 400KB, L2-resident) ----
__global__ __launch_bounds__(256) void bucketE_kernel(int2* __restrict__ epack,
                                                      const float* __restrict__ dinv) {
    int tid = blockIdx.x * 256 + threadIdx.x;
    int stride = gridDim.x * 256;
    for (int i = tid; i < N_EDGES; i += stride) {
        int s = epack[i].x;
        epack[i] = make_int2(s, __float_as_int(dinv[s]));
    }
}

// ---------------- wpack: Weff collapsed + fp16 + MFMA B-fragment order ----------------
// Fragment (s,nt): lane l, elem j holds B[k=32s+(l>>4)*8+j][n=nt*16+(l&15)]
__global__ __launch_bounds__(256) void wpack_kernel(const float* __restrict__ thetas,
                                                    const float* __restrict__ Wm1,
                                                    __half* __restrict__ Bpack) {
    int u = blockIdx.x * 256 + threadIdx.x;   // 16384 total
    int j = u & 7, lane = (u >> 3) & 63, frag = u >> 9;
    int nt = frag & 3, s = frag >> 2;
    int k = 32 * s + ((lane >> 4) << 3) + j;
    int q = k >> 6, f = k & 63;
    int n = nt * 16 + (lane & 15);
    float acc = 0.f;
    #pragma unroll
    for (int c = 0; c < 3; ++c)
        acc = fmaf(thetas[c * 4 + q], Wm1[(c * 64 + f) * 64 + n], acc);
    Bpack[u] = __float2half(acc);
}

// ---------------- trunk: h = relu(relu(X@W1+b1)@W2+b2) -> half table L0h ----------------
__global__ __launch_bounds__(256) void trunk_kernel(
    const float* __restrict__ X, const float* __restrict__ W1, const float* __restrict__ b1,
    const float* __restrict__ W2, const float* __restrict__ b2, __half* __restrict__ H)
{
    __shared__ float stage[16][IN_FEATS];   // 8 KB
    __shared__ float part[4][16][64];       // 16 KB
    __shared__ float h1s[16][64];           // 4 KB
    int t = threadIdx.x;
    int wv = __builtin_amdgcn_readfirstlane(t >> 6);
    int lane = t & 63;
    float w1r[32], w2r[16];
    #pragma unroll
    for (int i = 0; i < 32; ++i) w1r[i] = W1[(wv * 32 + i) * 64 + lane];
    #pragma unroll
    for (int i = 0; i < 16; ++i) w2r[i] = W2[(wv * 16 + i) * 64 + lane];
    float b1v = b1[lane], b2v = b2[lane];
    int srow = t >> 5, sf4 = t & 31;
    float4* st4 = (float4*)stage;

    for (int batch = 0; batch < 4; ++batch) {
        int row0 = blockIdx.x * 64 + batch * 16;
        #pragma unroll
        for (int p = 0; p < 2; ++p) {
            int row = row0 + srow + 8 * p;
            if (row >= N_NODES) row = N_NODES - 1;
            st4[t + 256 * p] =
                ((const float4*)(X + (size_t)row * IN_FEATS))[sf4];
        }
        __syncthreads();
        float acc[16];
        #pragma unroll
        for (int r = 0; r < 16; ++r) {
            const float4* xb = (const float4*)&stage[r][wv * 32];   // uniform -> broadcast
            float a = 0.f, b = 0.f;
            #pragma unroll
            for (int i4 = 0; i4 < 8; i4 += 2) {
                float4 v0 = xb[i4], v1 = xb[i4 + 1];
                a = fmaf(v0.x, w1r[i4 * 4 + 0], a);
                a = fmaf(v0.y, w1r[i4 * 4 + 1], a);
                a = fmaf(v0.z, w1r[i4 * 4 + 2], a);
                a = fmaf(v0.w, w1r[i4 * 4 + 3], a);
                b = fmaf(v1.x, w1r[i4 * 4 + 4], b);
                b = fmaf(v1.y, w1r[i4 * 4 + 5], b);
                b = fmaf(v1.z, w1r[i4 * 4 + 6], b);
                b = fmaf(v1.w, w1r[i4 * 4 + 7], b);
            }
            acc[r] = a + b;
        }
        #pragma unroll
        for (int r = 0; r < 16; ++r) part[wv][r][lane] = acc[r];
        __syncthreads();
        #pragma unroll
        for (int rr = 0; rr < 4; ++rr) {
            int r = wv * 4 + rr;
            float y1 = part[0][r][lane] + part[1][r][lane] +
                       part[2][r][lane] + part[3][r][lane] + b1v;
            h1s[r][lane] = fmaxf(y1, 0.f);
        }
        __syncthreads();
        float acc2[16];
        #pragma unroll
        for (int r = 0; r < 16; ++r) {
            const float4* xb = (const float4*)&h1s[r][wv * 16];     // uniform -> broadcast
            float a = 0.f, b = 0.f;
            #pragma unroll
            for (int i4 = 0; i4 < 4; i4 += 2) {
                float4 v0 = xb[i4], v1 = xb[i4 + 1];
                a = fmaf(v0.x, w2r[i4 * 4 + 0], a);
                a = fmaf(v0.y, w2r[i4 * 4 + 1], a);
                a = fmaf(v0.z, w2r[i4 * 4 + 2], a);
                a = fmaf(v0.w, w2r[i4 * 4 + 3], a);
                b = fmaf(v1.x, w2r[i4 * 4 + 4], b);
                b = fmaf(v1.y, w2r[i4 * 4 + 5], b);
                b = fmaf(v1.z, w2r[i4 * 4 + 6], b);
                b = fmaf(v1.w, w2r[i4 * 4 + 7], b);
            }
            acc2[r] = a + b;
        }
        __syncthreads();
        #pragma unroll
        for (int r = 0; r < 16; ++r) part[wv][r][lane] = acc2[r];
        __syncthreads();
        #pragma unroll
        for (int rr = 0; rr < 4; ++rr) {
            int r = wv * 4 + rr;
            int row = row0 + r;
            float y2 = part[0][r][lane] + part[1][r][lane] +
                       part[2][r][lane] + part[3][r][lane] + b2v;
            if (row < N_NODES) H[(size_t)row * 64 + lane] = __float2half(fmaxf(y2, 0.f));
        }
        __syncthreads();
    }
}

// ---------------- gather pass: Fnew[n] = Fprev[n] - dinv[n]*sum_e w_e*Fprev[s_e]
// half tables (128B row per edge), fp32 accumulate; one wave per node.
__global__ __launch_bounds__(256) void gather_kernel(
    const __half* __restrict__ Fprev, const int* __restrict__ rowp,
    const int2* __restrict__ epack, const float* __restrict__ dinv,
    __half* __restrict__ Fnew)
{
    int wv = __builtin_amdgcn_readfirstlane(threadIdx.x >> 6);
    int wid = blockIdx.x * 4 + wv;   // node id (uniform)
    int lane = threadIdx.x & 63;
    int beg = rowp[wid], end = rowp[wid + 1];
    float acc = 0.0f;
    int j = beg;
    for (; j + 7 < end; j += 8) {
        int2 e0 = epack[j],     e1 = epack[j + 1], e2 = epack[j + 2], e3 = epack[j + 3];
        int2 e4 = epack[j + 4], e5 = epack[j + 5], e6 = epack[j + 6], e7 = epack[j + 7];
        float v0 = __half2float(Fprev[(size_t)e0.x * 64 + lane]);
        float v1 = __half2float(Fprev[(size_t)e1.x * 64 + lane]);
        float v2 = __half2float(Fprev[(size_t)e2.x * 64 + lane]);
        float v3 = __half2float(Fprev[(size_t)e3.x * 64 + lane]);
        float v4 = __half2float(Fprev[(size_t)e4.x * 64 + lane]);
        float v5 = __half2float(Fprev[(size_t)e5.x * 64 + lane]);
        float v6 = __half2float(Fprev[(size_t)e6.x * 64 + lane]);
        float v7 = __half2float(Fprev[(size_t)e7.x * 64 + lane]);
        acc = fmaf(v0, __int_as_float(e0.y), acc);
        acc = fmaf(v1, __int_as_float(e1.y), acc);
        acc = fmaf(v2, __int_as_float(e2.y), acc);
        acc = fmaf(v3, __int_as_float(e3.y), acc);
        acc = fmaf(v4, __int_as_float(e4.y), acc);
        acc = fmaf(v5, __int_as_float(e5.y), acc);
        acc = fmaf(v6, __int_as_float(e6.y), acc);
        acc = fmaf(v7, __int_as_float(e7.y), acc);
    }
    for (; j < end; ++j) {
        int2 e = epack[j];
        acc = fmaf(__half2float(Fprev[(size_t)e.x * 64 + lane]), __int_as_float(e.y), acc);
    }
    float self = __half2float(Fprev[(size_t)wid * 64 + lane]);
    Fnew[(size_t)wid * 64 + lane] = __float2half(self - acc * dinv[wid]);
}

// ---------------- final (MFMA): out = relu(A@B + bm1) @ Wm2 + bm2 ----------------
// A[100000 x 256] fp16 = [L0|L1|L2|L3] column-blocked (Lh contiguous);
// B[256 x 64] fp16 pre-packed in fragment order (Bpack).
// D: col n = nt*16 + (l&15), row = row0 + (l>>4)*4 + reg   [m89 layout]
__global__ __launch_bounds__(256) void final_mfma_kernel(
    const __half* __restrict__ L0h, const __half* __restrict__ Bpack,
    const float* __restrict__ Wm2, const float* __restrict__ bm1,
    const float* __restrict__ bm2, float* __restrict__ out)
{
    const size_t NH = (size_t)N_NODES * 64;
    int t = threadIdx.x;
    int wv = t >> 6;
    int lane = t & 63;
    int gw = blockIdx.x * 4 + wv;          // 1564 waves

    const f16x8* bp = (const f16x8*)Bpack;
    f16x8 b[4][8];
    #pragma unroll
    for (int s = 0; s < 8; ++s)
        #pragma unroll
        for (int nt = 0; nt < 4; ++nt)
            b[nt][s] = bp[(s * 4 + nt) * 64 + lane];

    float bm1v[4], w20[4], w21[4];
    #pragma unroll
    for (int nt = 0; nt < 4; ++nt) {
        int n = nt * 16 + (lane & 15);
        bm1v[nt] = bm1[n];
        w20[nt] = Wm2[n * 2 + 0];
        w21[nt] = Wm2[n * 2 + 1];
    }
    float bm20 = bm2[0], bm21 = bm2[1];

    for (int u = 0; u < 4; ++u) {
        int tile = gw * 4 + u;
        if (tile >= 6250) break;           // 6250 * 16 = 100000 exactly
        int row0 = tile * 16;
        const __half* abase = L0h + (size_t)(row0 + (lane & 15)) * 64 + ((lane >> 4) << 3);
        f16x8 a[8];
        #pragma unroll
        for (int s = 0; s < 8; ++s)
            a[s] = *(const f16x8*)(abase + (size_t)(s >> 1) * NH + 32 * (s & 1));
        f32x4 acc[4];
        #pragma unroll
        for (int nt = 0; nt < 4; ++nt) acc[nt] = (f32x4){0.f, 0.f, 0.f, 0.f};
        #pragma unroll
        for (int s = 0; s < 8; ++s)
            #pragma unroll
            for (int nt = 0; nt < 4; ++nt)
                acc[nt] = __builtin_amdgcn_mfma_f32_16x16x32_f16(a[s], b[nt][s], acc[nt], 0, 0, 0);
        float o0[4], o1[4];
        #pragma unroll
        for (int reg = 0; reg < 4; ++reg) { o0[reg] = 0.f; o1[reg] = 0.f; }
        #pragma unroll
        for (int nt = 0; nt < 4; ++nt)
            #pragma unroll
            for (int reg = 0; reg < 4; ++reg) {
                float v = fmaxf(acc[nt][reg] + bm1v[nt], 0.f);
                o0[reg] = fmaf(v, w20[nt], o0[reg]);
                o1[reg] = fmaf(v, w21[nt], o1[reg]);
            }
        #pragma unroll
        for (int reg = 0; reg < 4; ++reg) {
            #pragma unroll
            for (int m = 8; m > 0; m >>= 1) {
                o0[reg] += __shfl_xor(o0[reg], m);
                o1[reg] += __shfl_xor(o1[reg], m);
            }
        }
        if ((lane & 15) == 0) {
            int rbase = row0 + (lane >> 4) * 4;
            #pragma unroll
            for (int reg = 0; reg < 4; ++reg) {
                out[(rbase + reg) * 2 + 0] = o0[reg] + bm20;
                out[(rbase + reg) * 2 + 1] = o1[reg] + bm21;
            }
        }
    }
}

extern "C" void kernel_launch(void* const* d_in, const int* in_sizes, int n_in,
                              void* d_out, int out_size, void* d_ws, size_t ws_size,
                              hipStream_t stream)
{
    const float* feature = (const float*)d_in[0];
    const int*   src     = (const int*)d_in[1];
    const int*   dst     = (const int*)d_in[2];
    const float* W1      = (const float*)d_in[3];
    const float* b1      = (const float*)d_in[4];
    const float* W2      = (const float*)d_in[5];
    const float* b2      = (const float*)d_in[6];
    const float* thetas  = (const float*)d_in[7];
    const float* Wm1     = (const float*)d_in[8];
    const float* bm1     = (const float*)d_in[9];
    const float* Wm2     = (const float*)d_in[10];
    const float* bm2     = (const float*)d_in[11];
    float* out = (float*)d_out;

    const size_t NH = (size_t)N_NODES * H_FEATS;   // 6.4M elems
    const int NPAD = 100352;
    float*  dinv    = (float*)d_ws;                   // N
    int*    rowp    = (int*)(dinv + NPAD);            // N+1
    int*    blkcnt  = rowp + NPAD;                    // 512*500 = 256K ints (1 MB)
    int*    boff    = blkcnt + NBA * NBUK;            // 512*500 (1 MB)
    int*    buktot  = boff + NBA * NBUK;              // 500
    int*    bukbase = buktot + 512;                   // 500
    int2*   ebuck   = (int2*)(bukbase + 512);         // E int2 (12.8 MB)
    int2*   epack   = ebuck + N_EDGES;                // E int2 (12.8 MB)
    __half* Lh      = (__half*)(epack + N_EDGES);     // 4 x NH halfs (51.2 MB)
    __half* Bpack   = Lh + 4 * NH;                    // 16384 halfs (32 KB)
    // total ws use ≈ 80 MB; no memsets needed (every array fully written before read)

    wpack_kernel<<<64, 256, 0, stream>>>(thetas, Wm1, Bpack);
    trunk_kernel<<<1563, 256, 0, stream>>>(feature, W1, b1, W2, b2, Lh);  // -> L0h

    bucketA_kernel<<<NBA, 256, 0, stream>>>(dst, blkcnt);
    bucketB1_kernel<<<NBUK, 512, 0, stream>>>(blkcnt, boff, buktot);
    bucketB2_kernel<<<1, 512, 0, stream>>>(buktot, bukbase, rowp);
    bucketC_kernel<<<NBA, 256, 0, stream>>>(src, dst, boff, bukbase, ebuck);
    bucketD_kernel<<<NBUK, 256, 0, stream>>>(ebuck, bukbase, buktot, rowp, dinv, epack);
    bucketE_kernel<<<2048, 256, 0, stream>>>(epack, dinv);

    for (int k = 1; k <= 3; ++k)
        gather_kernel<<<25000, 256, 0, stream>>>(Lh + (size_t)(k - 1) * NH, rowp, epack,
                                                 dinv, Lh + (size_t)k * NH);

    final_mfma_kernel<<<391, 256, 0, stream>>>(Lh, Bpack, Wm2, bm1, bm2, out);
}

// Round 18
// 245.327 us; speedup vs baseline: 1.4625x; 1.1667x over previous
//
#include <hip/hip_runtime.h>
#include <hip/hip_fp16.h>
#include <math.h>

#define N_NODES 100000
#define N_EDGES 1600000
#define IN_FEATS 128
#define H_FEATS 64
#define NBUK 500          // buckets
#define BSZ 200           // nodes per bucket (500*200 = 100000)
#define NBA 512           // blocks for count/scatter
#define ACHUNK 3125       // 512*3125 = 1600000 exactly

typedef _Float16 f16x8 __attribute__((ext_vector_type(8)));
typedef float f32x4 __attribute__((ext_vector_type(4)));

// ---------------- A: per-block bucket histogram (LDS atomics only) ----------------
__global__ __launch_bounds__(256) void bucketA_kernel(const int* __restrict__ dst,
                                                      int* __restrict__ blkcnt) {
    __shared__ int cnt[NBUK];
    int t = threadIdx.x;
    for (int i = t; i < NBUK; i += 256) cnt[i] = 0;
    __syncthreads();
    int e0 = blockIdx.x * ACHUNK;
    for (int e = e0 + t; e < e0 + ACHUNK; e += 256)
        atomicAdd(&cnt[dst[e] / BSZ], 1);
    __syncthreads();
    for (int i = t; i < NBUK; i += 256)
        blkcnt[blockIdx.x * NBUK + i] = cnt[i];   // coalesced
}

// ---------------- B1: per-bucket exclusive scan over blocks + totals ----------------
__global__ __launch_bounds__(512) void bucketB1_kernel(const int* __restrict__ blkcnt,
                                                       int* __restrict__ boff,
                                                       int* __restrict__ buktot) {
    __shared__ int tmp[512];
    int b = blockIdx.x;      // bucket
    int t = threadIdx.x;     // block index
    int v = blkcnt[t * NBUK + b];
    tmp[t] = v;
    __syncthreads();
    #pragma unroll
    for (int off = 1; off < 512; off <<= 1) {
        int x = (t >= off) ? tmp[t - off] : 0;
        __syncthreads();
        tmp[t] += x;
        __syncthreads();
    }
    boff[t * NBUK + b] = tmp[t] - v;
    if (t == 511) buktot[b] = tmp[511];
}

// ---------------- B2: exclusive scan of bucket totals ----------------
__global__ __launch_bounds__(512) void bucketB2_kernel(const int* __restrict__ buktot,
                                                       int* __restrict__ bukbase,
                                                       int* __restrict__ rowp) {
    __shared__ int tmp[512];
    int t = threadIdx.x;
    int v = (t < NBUK) ? buktot[t] : 0;
    tmp[t] = v;
    __syncthreads();
    #pragma unroll
    for (int off = 1; off < 512; off <<= 1) {
        int x = (t >= off) ? tmp[t - off] : 0;
        __syncthreads();
        tmp[t] += x;
        __syncthreads();
    }
    if (t < NBUK) bukbase[t] = tmp[t] - v;
    if (t == 0) rowp[N_NODES] = N_EDGES;
}

// ---------------- C: scatter edges into bucket-sorted ebuck ----------------
__global__ __launch_bounds__(256) void bucketC_kernel(const int* __restrict__ src,
                                                      const int* __restrict__ dst,
                                                      const int* __restrict__ boff,
                                                      const int* __restrict__ bukbase,
                                                      int2* __restrict__ ebuck) {
    __shared__ int sbase[NBUK];
    __shared__ int cur[NBUK];
    int t = threadIdx.x;
    for (int i = t; i < NBUK; i += 256) {
        sbase[i] = bukbase[i] + boff[blockIdx.x * NBUK + i];
        cur[i] = 0;
    }
    __syncthreads();
    int e0 = blockIdx.x * ACHUNK;
    for (int e = e0 + t; e < e0 + ACHUNK; e += 256) {
        int d = dst[e];
        int b = d / BSZ;
        int r = atomicAdd(&cur[b], 1);
        ebuck[sbase[b] + r] = make_int2(src[e], d);
    }
}

// ---------------- D: per-bucket fine CSR (all in LDS) ----------------
__global__ __launch_bounds__(256) void bucketD_kernel(const int2* __restrict__ ebuck,
                                                      const int* __restrict__ bukbase,
                                                      const int* __restrict__ buktot,
                                                      int* __restrict__ rowp,
                                                      float* __restrict__ dinv,
                                                      int2* __restrict__ epack) {
    __shared__ int deg[BSZ];
    __shared__ int tmp[256];
    __shared__ int nodeoff[BSZ];
    __shared__ int cur2[BSZ];
    int t = threadIdx.x;
    int buk = blockIdx.x;
    int nlo = buk * BSZ;
    int base = bukbase[buk];
    int cnt = buktot[buk];
    for (int i = t; i < BSZ; i += 256) { deg[i] = 0; cur2[i] = 0; }
    __syncthreads();
    for (int k = t; k < cnt; k += 256)
        atomicAdd(&deg[ebuck[base + k].y - nlo], 1);
    __syncthreads();
    int v = (t < BSZ) ? deg[t] : 0;
    tmp[t] = v;
    __syncthreads();
    #pragma unroll
    for (int off = 1; off < 256; off <<= 1) {
        int x = (t >= off) ? tmp[t - off] : 0;
        __syncthreads();
        tmp[t] += x;
        __syncthreads();
    }
    if (t < BSZ) {
        nodeoff[t] = tmp[t] - v;
        rowp[nlo + t] = base + tmp[t] - v;
        dinv[nlo + t] = rsqrtf(fmaxf((float)v, 1.0f));
    }
    __syncthreads();
    for (int k = t; k < cnt; k += 256) {
        int2 e = ebuck[base + k];
        int ld = e.y - nlo;
        int r = atomicAdd(&cur2[ld], 1);
        epack[base + nodeoff[ld] + r] = make_int2(e.x, 0);
    }
}

// ---------------- E: fill epack.y = bits(dinv[src]) (dinv is 400KB, L2-resident) ----
__global__ __launch_bounds__(256) void bucketE_kernel(int2* __restrict__ epack,
                                                      const float* __restrict__ dinv) {
    int tid = blockIdx.x * 256 + threadIdx.x;
    int stride = gridDim.x * 256;
    for (int i = tid; i < N_EDGES; i += stride) {
        int s = epack[i].x;
        epack[i] = make_int2(s, __float_as_int(dinv[s]));
    }
}

// ---------------- prep: pack Weff/W1/W2 into fp16 MFMA B-fragment order ----------------
// Fragment (s,nt): lane l, elem j holds B[k = 32s + (l>>4)*8 + j][n = nt*16 + (l&15)]
// Bpack: B = Weff (K=256, 16 frags); W1p: B = W1 (K=128, 16 frags); W2p: B = W2 (K=64, 8 frags)
__global__ __launch_bounds__(256) void prep_kernel(const float* __restrict__ thetas,
                                                   const float* __restrict__ Wm1,
                                                   const float* __restrict__ W1,
                                                   const float* __restrict__ W2,
                                                   __half* __restrict__ Bpack,
                                                   __half* __restrict__ W1p,
                                                   __half* __restrict__ W2p) {
    int u = blockIdx.x * 256 + threadIdx.x;
    if (u < 16384) {
        int j = u & 7, lane = (u >> 3) & 63, frag = u >> 9;
        int nt = frag & 3, s = frag >> 2;
        int k = 32 * s + ((lane >> 4) << 3) + j;
        int q = k >> 6, f = k & 63;
        int n = nt * 16 + (lane & 15);
        float acc = 0.f;
        #pragma unroll
        for (int c = 0; c < 3; ++c)
            acc = fmaf(thetas[c * 4 + q], Wm1[(c * 64 + f) * 64 + n], acc);
        Bpack[u] = __float2half(acc);
    } else if (u < 16384 + 8192) {
        int v = u - 16384;
        int j = v & 7, lane = (v >> 3) & 63, frag = v >> 9;   // frag 0..15
        int nt = frag & 3, s = frag >> 2;
        int k = 32 * s + ((lane >> 4) << 3) + j;              // 0..127
        int n = nt * 16 + (lane & 15);
        W1p[v] = __float2half(W1[k * 64 + n]);
    } else if (u < 16384 + 8192 + 4096) {
        int v = u - 24576;
        int j = v & 7, lane = (v >> 3) & 63, frag = v >> 9;   // frag 0..7
        int nt = frag & 3, s2 = frag >> 2;
        int k = 32 * s2 + ((lane >> 4) << 3) + j;             // 0..63
        int n = nt * 16 + (lane & 15);
        W2p[v] = __float2half(W2[k * 64 + n]);
    }
}

// ---------------- trunk (MFMA): H = fp16(relu(relu(X@W1+b1)@W2+b2)) ----------------
// One wave per 16-row tile, 2 tiles/wave. Layer1: A from fp32 X converted inline
// (K=128, 16 MFMA); D -> relu -> 2KB per-wave XOR-swizzled LDS -> A-frags for
// layer2 (K=64, 8 MFMA); D -> relu -> LDS -> coalesced 16B/lane H write.
// Layouts identical to final_mfma (verified): A[row=l&15][k=(l>>4)*8+j],
// D col=lane&15 (n=nt*16+..), row=(lane>>4)*4+reg. Swizzle: byte ^= (row&7)<<4.
__global__ __launch_bounds__(256) void trunk_mfma_kernel(
    const float* __restrict__ X, const __half* __restrict__ W1p, const float* __restrict__ b1,
    const __half* __restrict__ W2p, const float* __restrict__ b2, __half* __restrict__ H)
{
    __shared__ __half hl[4][1024];   // 2 KB per wave
    int t = threadIdx.x;
    int wv = t >> 6, lane = t & 63;
    int r_lo = lane & 15;            // A-frag row / D col
    int g = lane >> 4;               // k-group / D row group
    char* myl = (char*)hl[wv];

    const f16x8* w1f = (const f16x8*)W1p;
    const f16x8* w2f = (const f16x8*)W2p;
    f16x8 w1b[16], w2b[8];
    #pragma unroll
    for (int f = 0; f < 16; ++f) w1b[f] = w1f[f * 64 + lane];
    #pragma unroll
    for (int f = 0; f < 8; ++f)  w2b[f] = w2f[f * 64 + lane];
    float b1v[4], b2v[4];
    #pragma unroll
    for (int nt = 0; nt < 4; ++nt) {
        b1v[nt] = b1[nt * 16 + r_lo];
        b2v[nt] = b2[nt * 16 + r_lo];
    }

    int gw = blockIdx.x * 4 + wv;            // 782*4 = 3128 waves
    for (int u = 0; u < 2; ++u) {
        int tile = gw * 2 + u;
        if (tile >= 6250) break;             // 6250*16 = 100000 exactly
        int row0 = tile * 16;
        // layer 1: load + convert A, 16 MFMA
        const float* xb = X + (size_t)(row0 + r_lo) * IN_FEATS + g * 8;
        f16x8 a1[4];
        #pragma unroll
        for (int s = 0; s < 4; ++s) {
            float4 f0 = *(const float4*)(xb + 32 * s);
            float4 f1 = *(const float4*)(xb + 32 * s + 4);
            f16x8 a;
            a[0] = (_Float16)f0.x; a[1] = (_Float16)f0.y;
            a[2] = (_Float16)f0.z; a[3] = (_Float16)f0.w;
            a[4] = (_Float16)f1.x; a[5] = (_Float16)f1.y;
            a[6] = (_Float16)f1.z; a[7] = (_Float16)f1.w;
            a1[s] = a;
        }
        f32x4 acc1[4];
        #pragma unroll
        for (int nt = 0; nt < 4; ++nt) acc1[nt] = (f32x4){0.f, 0.f, 0.f, 0.f};
        #pragma unroll
        for (int s = 0; s < 4; ++s)
            #pragma unroll
            for (int nt = 0; nt < 4; ++nt)
                acc1[nt] = __builtin_amdgcn_mfma_f32_16x16x32_f16(a1[s], w1b[s * 4 + nt], acc1[nt], 0, 0, 0);
        // relu + bias -> swizzled LDS
        #pragma unroll
        for (int nt = 0; nt < 4; ++nt)
            #pragma unroll
            for (int reg = 0; reg < 4; ++reg) {
                int r = g * 4 + reg;
                int c = nt * 16 + r_lo;
                int byte = (r * 128 + c * 2) ^ ((r & 7) << 4);
                *(__half*)(myl + byte) = __float2half(fmaxf(acc1[nt][reg] + b1v[nt], 0.f));
            }
        // layer 2: A-frags from LDS (conflict-free by swizzle), 8 MFMA
        f16x8 a2[2];
        #pragma unroll
        for (int s2 = 0; s2 < 2; ++s2) {
            int byte = (r_lo * 128 + 64 * s2 + g * 16) ^ ((r_lo & 7) << 4);
            a2[s2] = *(const f16x8*)(myl + byte);
        }
        f32x4 acc2[4];
        #pragma unroll
        for (int nt = 0; nt < 4; ++nt) acc2[nt] = (f32x4){0.f, 0.f, 0.f, 0.f};
        #pragma unroll
        for (int s2 = 0; s2 < 2; ++s2)
            #pragma unroll
            for (int nt = 0; nt < 4; ++nt)
                acc2[nt] = __builtin_amdgcn_mfma_f32_16x16x32_f16(a2[s2], w2b[s2 * 4 + nt], acc2[nt], 0, 0, 0);
        // relu + bias -> swizzled LDS (overwrite)
        #pragma unroll
        for (int nt = 0; nt < 4; ++nt)
            #pragma unroll
            for (int reg = 0; reg < 4; ++reg) {
                int r = g * 4 + reg;
                int c = nt * 16 + r_lo;
                int byte = (r * 128 + c * 2) ^ ((r & 7) << 4);
                *(__half*)(myl + byte) = __float2half(fmaxf(acc2[nt][reg] + b2v[nt], 0.f));
            }
        // linear readback + coalesced global write (2 halves of the 2KB tile)
        #pragma unroll
        for (int h2 = 0; h2 < 2; ++h2) {
            int R = (lane >> 3) + 8 * h2;    // row 0..15
            int w = lane & 7;                // 16B slot
            int byte = (R * 128 + 16 * (w ^ (R & 7)));
            f16x8 hv = *(const f16x8*)(myl + byte);
            *(f16x8*)(H + (size_t)(row0 + R) * 64 + w * 8) = hv;
        }
    }
}

// ---------------- gather pass: Fnew[n] = Fprev[n] - dinv[n]*sum_e w_e*Fprev[s_e]
// half tables (128B row per edge), fp32 accumulate; one wave per node.
__global__ __launch_bounds__(256) void gather_kernel(
    const __half* __restrict__ Fprev, const int* __restrict__ rowp,
    const int2* __restrict__ epack, const float* __restrict__ dinv,
    __half* __restrict__ Fnew)
{
    int wv = __builtin_amdgcn_readfirstlane(threadIdx.x >> 6);
    int wid = blockIdx.x * 4 + wv;   // node id (uniform)
    int lane = threadIdx.x & 63;
    int beg = rowp[wid], end = rowp[wid + 1];
    float acc = 0.0f;
    int j = beg;
    for (; j + 7 < end; j += 8) {
        int2 e0 = epack[j],     e1 = epack[j + 1], e2 = epack[j + 2], e3 = epack[j + 3];
        int2 e4 = epack[j + 4], e5 = epack[j + 5], e6 = epack[j + 6], e7 = epack[j + 7];
        float v0 = __half2float(Fprev[(size_t)e0.x * 64 + lane]);
        float v1 = __half2float(Fprev[(size_t)e1.x * 64 + lane]);
        float v2 = __half2float(Fprev[(size_t)e2.x * 64 + lane]);
        float v3 = __half2float(Fprev[(size_t)e3.x * 64 + lane]);
        float v4 = __half2float(Fprev[(size_t)e4.x * 64 + lane]);
        float v5 = __half2float(Fprev[(size_t)e5.x * 64 + lane]);
        float v6 = __half2float(Fprev[(size_t)e6.x * 64 + lane]);
        float v7 = __half2float(Fprev[(size_t)e7.x * 64 + lane]);
        acc = fmaf(v0, __int_as_float(e0.y), acc);
        acc = fmaf(v1, __int_as_float(e1.y), acc);
        acc = fmaf(v2, __int_as_float(e2.y), acc);
        acc = fmaf(v3, __int_as_float(e3.y), acc);
        acc = fmaf(v4, __int_as_float(e4.y), acc);
        acc = fmaf(v5, __int_as_float(e5.y), acc);
        acc = fmaf(v6, __int_as_float(e6.y), acc);
        acc = fmaf(v7, __int_as_float(e7.y), acc);
    }
    for (; j < end; ++j) {
        int2 e = epack[j];
        acc = fmaf(__half2float(Fprev[(size_t)e.x * 64 + lane]), __int_as_float(e.y), acc);
    }
    float self = __half2float(Fprev[(size_t)wid * 64 + lane]);
    Fnew[(size_t)wid * 64 + lane] = __float2half(self - acc * dinv[wid]);
}

// ---------------- final (MFMA): out = relu(A@B + bm1) @ Wm2 + bm2 ----------------
// A[100000 x 256] fp16 = [L0|L1|L2|L3] column-blocked (Lh contiguous);
// B[256 x 64] fp16 pre-packed in fragment order (Bpack).
// D: col n = nt*16 + (l&15), row = row0 + (l>>4)*4 + reg   [m89 layout]
__global__ __launch_bounds__(256) void final_mfma_kernel(
    const __half* __restrict__ L0h, const __half* __restrict__ Bpack,
    const float* __restrict__ Wm2, const float* __restrict__ bm1,
    const float* __restrict__ bm2, float* __restrict__ out)
{
    const size_t NH = (size_t)N_NODES * 64;
    int t = threadIdx.x;
    int wv = t >> 6;
    int lane = t & 63;
    int gw = blockIdx.x * 4 + wv;          // 1564 waves

    const f16x8* bp = (const f16x8*)Bpack;
    f16x8 b[4][8];
    #pragma unroll
    for (int s = 0; s < 8; ++s)
        #pragma unroll
        for (int nt = 0; nt < 4; ++nt)
            b[nt][s] = bp[(s * 4 + nt) * 64 + lane];

    float bm1v[4], w20[4], w21[4];
    #pragma unroll
    for (int nt = 0; nt < 4; ++nt) {
        int n = nt * 16 + (lane & 15);
        bm1v[nt] = bm1[n];
        w20[nt] = Wm2[n * 2 + 0];
        w21[nt] = Wm2[n * 2 + 1];
    }
    float bm20 = bm2[0], bm21 = bm2[1];

    for (int u = 0; u < 4; ++u) {
        int tile = gw * 4 + u;
        if (tile >= 6250) break;           // 6250 * 16 = 100000 exactly
        int row0 = tile * 16;
        const __half* abase = L0h + (size_t)(row0 + (lane & 15)) * 64 + ((lane >> 4) << 3);
        f16x8 a[8];
        #pragma unroll
        for (int s = 0; s < 8; ++s)
            a[s] = *(const f16x8*)(abase + (size_t)(s >> 1) * NH + 32 * (s & 1));
        f32x4 acc[4];
        #pragma unroll
        for (int nt = 0; nt < 4; ++nt) acc[nt] = (f32x4){0.f, 0.f, 0.f, 0.f};
        #pragma unroll
        for (int s = 0; s < 8; ++s)
            #pragma unroll
            for (int nt = 0; nt < 4; ++nt)
                acc[nt] = __builtin_amdgcn_mfma_f32_16x16x32_f16(a[s], b[nt][s], acc[nt], 0, 0, 0);
        float o0[4], o1[4];
        #pragma unroll
        for (int reg = 0; reg < 4; ++reg) { o0[reg] = 0.f; o1[reg] = 0.f; }
        #pragma unroll
        for (int nt = 0; nt < 4; ++nt)
            #pragma unroll
            for (int reg = 0; reg < 4; ++reg) {
                float v = fmaxf(acc[nt][reg] + bm1v[nt], 0.f);
                o0[reg] = fmaf(v, w20[nt], o0[reg]);
                o1[reg] = fmaf(v, w21[nt], o1[reg]);
            }
        #pragma unroll
        for (int reg = 0; reg < 4; ++reg) {
            #pragma unroll
            for (int m = 8; m > 0; m >>= 1) {
                o0[reg] += __shfl_xor(o0[reg], m);
                o1[reg] += __shfl_xor(o1[reg], m);
            }
        }
        if ((lane & 15) == 0) {
            int rbase = row0 + (lane >> 4) * 4;
            #pragma unroll
            for (int reg = 0; reg < 4; ++reg) {
                out[(rbase + reg) * 2 + 0] = o0[reg] + bm20;
                out[(rbase + reg) * 2 + 1] = o1[reg] + bm21;
            }
        }
    }
}

extern "C" void kernel_launch(void* const* d_in, const int* in_sizes, int n_in,
                              void* d_out, int out_size, void* d_ws, size_t ws_size,
                              hipStream_t stream)
{
    const float* feature = (const float*)d_in[0];
    const int*   src     = (const int*)d_in[1];
    const int*   dst     = (const int*)d_in[2];
    const float* W1      = (const float*)d_in[3];
    const float* b1      = (const float*)d_in[4];
    const float* W2      = (const float*)d_in[5];
    const float* b2      = (const float*)d_in[6];
    const float* thetas  = (const float*)d_in[7];
    const float* Wm1     = (const float*)d_in[8];
    const float* bm1     = (const float*)d_in[9];
    const float* Wm2     = (const float*)d_in[10];
    const float* bm2     = (const float*)d_in[11];
    float* out = (float*)d_out;

    const size_t NH = (size_t)N_NODES * H_FEATS;   // 6.4M elems
    const int NPAD = 100352;
    float*  dinv    = (float*)d_ws;                   // N
    int*    rowp    = (int*)(dinv + NPAD);            // N+1
    int*    blkcnt  = rowp + NPAD;                    // 512*500 (1 MB)
    int*    boff    = blkcnt + NBA * NBUK;            // 512*500 (1 MB)
    int*    buktot  = boff + NBA * NBUK;              // 500
    int*    bukbase = buktot + 512;                   // 500
    int2*   ebuck   = (int2*)(bukbase + 512);         // E int2 (12.8 MB)
    int2*   epack   = ebuck + N_EDGES;                // E int2 (12.8 MB)
    __half* Lh      = (__half*)(epack + N_EDGES);     // 4 x NH halfs (51.2 MB)
    __half* Bpack   = Lh + 4 * NH;                    // 16384 halfs
    __half* W1p     = Bpack + 16384;                  // 8192 halfs
    __half* W2p     = W1p + 8192;                     // 4096 halfs
    // total ws use ≈ 80 MB; no memsets (every array fully written before read)

    prep_kernel<<<112, 256, 0, stream>>>(thetas, Wm1, W1, W2, Bpack, W1p, W2p);
    trunk_mfma_kernel<<<782, 256, 0, stream>>>(feature, W1p, b1, W2p, b2, Lh);  // -> L0h

    bucketA_kernel<<<NBA, 256, 0, stream>>>(dst, blkcnt);
    bucketB1_kernel<<<NBUK, 512, 0, stream>>>(blkcnt, boff, buktot);
    bucketB2_kernel<<<1, 512, 0, stream>>>(buktot, bukbase, rowp);
    bucketC_kernel<<<NBA, 256, 0, stream>>>(src, dst, boff, bukbase, ebuck);
    bucketD_kernel<<<NBUK, 256, 0, stream>>>(ebuck, bukbase, buktot, rowp, dinv, epack);
    bucketE_kernel<<<2048, 256, 0, stream>>>(epack, dinv);

    for (int k = 1; k <= 3; ++k)
        gather_kernel<<<25000, 256, 0, stream>>>(Lh + (size_t)(k - 1) * NH, rowp, epack,
                                                 dinv, Lh + (size_t)k * NH);

    final_mfma_kernel<<<391, 256, 0, stream>>>(Lh, Bpack, Wm2, bm1, bm2, out);
}

// Round 20
// 242.745 us; speedup vs baseline: 1.4780x; 1.0106x over previous
//
#include <hip/hip_runtime.h>
#include <hip/hip_fp16.h>
#include <math.h>

#define N_NODES 100000
#define N_EDGES 1600000
#define IN_FEATS 128
#define H_FEATS 64
#define NBUK 500          // buckets
#define BSZ 200           // nodes per bucket (500*200 = 100000)
#define NBA 512           // blocks for count/scatter
#define ACHUNK 3125       // 512*3125 = 1600000 exactly

typedef _Float16 f16x8 __attribute__((ext_vector_type(8)));
typedef float f32x4 __attribute__((ext_vector_type(4)));

// ---------------- A: per-block bucket histogram (LDS atomics only) ----------------
__global__ __launch_bounds__(256) void bucketA_kernel(const int* __restrict__ dst,
                                                      int* __restrict__ blkcnt) {
    __shared__ int cnt[NBUK];
    int t = threadIdx.x;
    for (int i = t; i < NBUK; i += 256) cnt[i] = 0;
    __syncthreads();
    int e0 = blockIdx.x * ACHUNK;
    for (int e = e0 + t; e < e0 + ACHUNK; e += 256)
        atomicAdd(&cnt[dst[e] / BSZ], 1);
    __syncthreads();
    for (int i = t; i < NBUK; i += 256)
        blkcnt[blockIdx.x * NBUK + i] = cnt[i];   // coalesced
}

// ---------------- B1: per-bucket exclusive scan over blocks + totals ----------------
__global__ __launch_bounds__(512) void bucketB1_kernel(const int* __restrict__ blkcnt,
                                                       int* __restrict__ boff,
                                                       int* __restrict__ buktot) {
    __shared__ int tmp[512];
    int b = blockIdx.x;      // bucket
    int t = threadIdx.x;     // block index
    int v = blkcnt[t * NBUK + b];
    tmp[t] = v;
    __syncthreads();
    #pragma unroll
    for (int off = 1; off < 512; off <<= 1) {
        int x = (t >= off) ? tmp[t - off] : 0;
        __syncthreads();
        tmp[t] += x;
        __syncthreads();
    }
    boff[t * NBUK + b] = tmp[t] - v;
    if (t == 511) buktot[b] = tmp[511];
}

// ---------------- B2: exclusive scan of bucket totals ----------------
__global__ __launch_bounds__(512) void bucketB2_kernel(const int* __restrict__ buktot,
                                                       int* __restrict__ bukbase,
                                                       int* __restrict__ rowp) {
    __shared__ int tmp[512];
    int t = threadIdx.x;
    int v = (t < NBUK) ? buktot[t] : 0;
    tmp[t] = v;
    __syncthreads();
    #pragma unroll
    for (int off = 1; off < 512; off <<= 1) {
        int x = (t >= off) ? tmp[t - off] : 0;
        __syncthreads();
        tmp[t] += x;
        __syncthreads();
    }
    if (t < NBUK) bukbase[t] = tmp[t] - v;
    if (t == 0) rowp[N_NODES] = N_EDGES;
}

// ---------------- C: scatter edges into bucket-sorted ebuck ----------------
__global__ __launch_bounds__(256) void bucketC_kernel(const int* __restrict__ src,
                                                      const int* __restrict__ dst,
                                                      const int* __restrict__ boff,
                                                      const int* __restrict__ bukbase,
                                                      int2* __restrict__ ebuck) {
    __shared__ int sbase[NBUK];
    __shared__ int cur[NBUK];
    int t = threadIdx.x;
    for (int i = t; i < NBUK; i += 256) {
        sbase[i] = bukbase[i] + boff[blockIdx.x * NBUK + i];
        cur[i] = 0;
    }
    __syncthreads();
    int e0 = blockIdx.x * ACHUNK;
    for (int e = e0 + t; e < e0 + ACHUNK; e += 256) {
        int d = dst[e];
        int b = d / BSZ;
        int r = atomicAdd(&cur[b], 1);
        ebuck[sbase[b] + r] = make_int2(src[e], d);
    }
}

// ---------------- D1: per-bucket degrees -> rowp (global slot base) + dinv ----------
__global__ __launch_bounds__(256) void bucketD1_kernel(const int2* __restrict__ ebuck,
                                                       const int* __restrict__ bukbase,
                                                       const int* __restrict__ buktot,
                                                       int* __restrict__ rowp,
                                                       float* __restrict__ dinv) {
    __shared__ int deg[BSZ];
    __shared__ int tmp[256];
    int t = threadIdx.x;
    int buk = blockIdx.x;
    int nlo = buk * BSZ;
    int base = bukbase[buk];
    int cnt = buktot[buk];
    for (int i = t; i < BSZ; i += 256) deg[i] = 0;
    __syncthreads();
    for (int k = t; k < cnt; k += 256)
        atomicAdd(&deg[ebuck[base + k].y - nlo], 1);
    __syncthreads();
    int v = (t < BSZ) ? deg[t] : 0;
    tmp[t] = v;
    __syncthreads();
    #pragma unroll
    for (int off = 1; off < 256; off <<= 1) {
        int x = (t >= off) ? tmp[t - off] : 0;
        __syncthreads();
        tmp[t] += x;
        __syncthreads();
    }
    if (t < BSZ) {
        rowp[nlo + t] = base + tmp[t] - v;
        dinv[nlo + t] = rsqrtf(fmaxf((float)v, 1.0f));
    }
}

// ---------------- D2: rank ebuck (L3-hot re-read) -> write epack once with final
// (src, bits(dinv[src])). dinv complete after D1; 400KB -> L2-resident reads. ----
__global__ __launch_bounds__(256) void bucketD2_kernel(const int2* __restrict__ ebuck,
                                                       const int* __restrict__ bukbase,
                                                       const int* __restrict__ buktot,
                                                       const int* __restrict__ rowp,
                                                       const float* __restrict__ dinv,
                                                       int2* __restrict__ epack) {
    __shared__ int rp[BSZ];
    __shared__ int cur2[BSZ];
    int t = threadIdx.x;
    int buk = blockIdx.x;
    int nlo = buk * BSZ;
    int base = bukbase[buk];
    int cnt = buktot[buk];
    for (int i = t; i < BSZ; i += 256) { rp[i] = rowp[nlo + i]; cur2[i] = 0; }
    __syncthreads();
    for (int k = t; k < cnt; k += 256) {
        int2 e = ebuck[base + k];
        int ld = e.y - nlo;
        int r = atomicAdd(&cur2[ld], 1);
        epack[rp[ld] + r] = make_int2(e.x, __float_as_int(dinv[e.x]));
    }
}

// ---------------- prep: pack Weff/W1/W2 into fp16 MFMA B-fragment order ----------------
// Fragment (s,nt): lane l, elem j holds B[k = 32s + (l>>4)*8 + j][n = nt*16 + (l&15)]
__global__ __launch_bounds__(256) void prep_kernel(const float* __restrict__ thetas,
                                                   const float* __restrict__ Wm1,
                                                   const float* __restrict__ W1,
                                                   const float* __restrict__ W2,
                                                   __half* __restrict__ Bpack,
                                                   __half* __restrict__ W1p,
                                                   __half* __restrict__ W2p) {
    int u = blockIdx.x * 256 + threadIdx.x;
    if (u < 16384) {
        int j = u & 7, lane = (u >> 3) & 63, frag = u >> 9;
        int nt = frag & 3, s = frag >> 2;
        int k = 32 * s + ((lane >> 4) << 3) + j;
        int q = k >> 6, f = k & 63;
        int n = nt * 16 + (lane & 15);
        float acc = 0.f;
        #pragma unroll
        for (int c = 0; c < 3; ++c)
            acc = fmaf(thetas[c * 4 + q], Wm1[(c * 64 + f) * 64 + n], acc);
        Bpack[u] = __float2half(acc);
    } else if (u < 16384 + 8192) {
        int v = u - 16384;
        int j = v & 7, lane = (v >> 3) & 63, frag = v >> 9;   // frag 0..15
        int nt = frag & 3, s = frag >> 2;
        int k = 32 * s + ((lane >> 4) << 3) + j;              // 0..127
        int n = nt * 16 + (lane & 15);
        W1p[v] = __float2half(W1[k * 64 + n]);
    } else if (u < 16384 + 8192 + 4096) {
        int v = u - 24576;
        int j = v & 7, lane = (v >> 3) & 63, frag = v >> 9;   // frag 0..7
        int nt = frag & 3, s2 = frag >> 2;
        int k = 32 * s2 + ((lane >> 4) << 3) + j;             // 0..63
        int n = nt * 16 + (lane & 15);
        W2p[v] = __float2half(W2[k * 64 + n]);
    }
}

// ---------------- trunk (MFMA): H = fp16(relu(relu(X@W1+b1)@W2+b2)) ----------------
// ONE 16-row tile per wave (6252 waves; TLP for latency hiding). Layouts identical
// to final_mfma (verified). Swizzle: byte ^= (row&7)<<4.
__global__ __launch_bounds__(256) void trunk_mfma_kernel(
    const float* __restrict__ X, const __half* __restrict__ W1p, const float* __restrict__ b1,
    const __half* __restrict__ W2p, const float* __restrict__ b2, __half* __restrict__ H)
{
    __shared__ __half hl[4][1024];   // 2 KB per wave
    int t = threadIdx.x;
    int wv = t >> 6, lane = t & 63;
    int r_lo = lane & 15;            // A-frag row / D col
    int g = lane >> 4;               // k-group / D row group
    char* myl = (char*)hl[wv];

    int tile = blockIdx.x * 4 + wv;
    if (tile >= 6250) return;        // 6250*16 = 100000 exactly; no barriers below

    const f16x8* w1f = (const f16x8*)W1p;
    const f16x8* w2f = (const f16x8*)W2p;
    f16x8 w1b[16], w2b[8];
    #pragma unroll
    for (int f = 0; f < 16; ++f) w1b[f] = w1f[f * 64 + lane];
    #pragma unroll
    for (int f = 0; f < 8; ++f)  w2b[f] = w2f[f * 64 + lane];
    float b1v[4], b2v[4];
    #pragma unroll
    for (int nt = 0; nt < 4; ++nt) {
        b1v[nt] = b1[nt * 16 + r_lo];
        b2v[nt] = b2[nt * 16 + r_lo];
    }

    int row0 = tile * 16;
    const float* xb = X + (size_t)(row0 + r_lo) * IN_FEATS + g * 8;
    f16x8 a1[4];
    #pragma unroll
    for (int s = 0; s < 4; ++s) {
        float4 f0 = *(const float4*)(xb + 32 * s);
        float4 f1 = *(const float4*)(xb + 32 * s + 4);
        f16x8 a;
        a[0] = (_Float16)f0.x; a[1] = (_Float16)f0.y;
        a[2] = (_Float16)f0.z; a[3] = (_Float16)f0.w;
        a[4] = (_Float16)f1.x; a[5] = (_Float16)f1.y;
        a[6] = (_Float16)f1.z; a[7] = (_Float16)f1.w;
        a1[s] = a;
    }
    f32x4 acc1[4];
    #pragma unroll
    for (int nt = 0; nt < 4; ++nt) acc1[nt] = (f32x4){0.f, 0.f, 0.f, 0.f};
    #pragma unroll
    for (int s = 0; s < 4; ++s)
        #pragma unroll
        for (int nt = 0; nt < 4; ++nt)
            acc1[nt] = __builtin_amdgcn_mfma_f32_16x16x32_f16(a1[s], w1b[s * 4 + nt], acc1[nt], 0, 0, 0);
    #pragma unroll
    for (int nt = 0; nt < 4; ++nt)
        #pragma unroll
        for (int reg = 0; reg < 4; ++reg) {
            int r = g * 4 + reg;
            int c = nt * 16 + r_lo;
            int byte = (r * 128 + c * 2) ^ ((r & 7) << 4);
            *(__half*)(myl + byte) = __float2half(fmaxf(acc1[nt][reg] + b1v[nt], 0.f));
        }
    f16x8 a2[2];
    #pragma unroll
    for (int s2 = 0; s2 < 2; ++s2) {
        int byte = (r_lo * 128 + 64 * s2 + g * 16) ^ ((r_lo & 7) << 4);
        a2[s2] = *(const f16x8*)(myl + byte);
    }
    f32x4 acc2[4];
    #pragma unroll
    for (int nt = 0; nt < 4; ++nt) acc2[nt] = (f32x4){0.f, 0.f, 0.f, 0.f};
    #pragma unroll
    for (int s2 = 0; s2 < 2; ++s2)
        #pragma unroll
        for (int nt = 0; nt < 4; ++nt)
            acc2[nt] = __builtin_amdgcn_mfma_f32_16x16x32_f16(a2[s2], w2b[s2 * 4 + nt], acc2[nt], 0, 0, 0);
    #pragma unroll
    for (int nt = 0; nt < 4; ++nt)
        #pragma unroll
        for (int reg = 0; reg < 4; ++reg) {
            int r = g * 4 + reg;
            int c = nt * 16 + r_lo;
            int byte = (r * 128 + c * 2) ^ ((r & 7) << 4);
            *(__half*)(myl + byte) = __float2half(fmaxf(acc2[nt][reg] + b2v[nt], 0.f));
        }
    #pragma unroll
    for (int h2 = 0; h2 < 2; ++h2) {
        int R = (lane >> 3) + 8 * h2;    // row 0..15
        int w = lane & 7;                // 16B slot
        int byte = (R * 128 + 16 * (w ^ (R & 7)));
        f16x8 hv = *(const f16x8*)(myl + byte);
        *(f16x8*)(H + (size_t)(row0 + R) * 64 + w * 8) = hv;
    }
}

// ---------------- gather pass: Fnew[n] = Fprev[n] - dinv[n]*sum_e w_e*Fprev[s_e]
// half tables (128B row per edge), fp32 accumulate; one wave per node.
__global__ __launch_bounds__(256) void gather_kernel(
    const __half* __restrict__ Fprev, const int* __restrict__ rowp,
    const int2* __restrict__ epack, const float* __restrict__ dinv,
    __half* __restrict__ Fnew)
{
    int wv = __builtin_amdgcn_readfirstlane(threadIdx.x >> 6);
    int wid = blockIdx.x * 4 + wv;   // node id (uniform)
    int lane = threadIdx.x & 63;
    int beg = rowp[wid], end = rowp[wid + 1];
    float acc = 0.0f;
    int j = beg;
    for (; j + 7 < end; j += 8) {
        int2 e0 = epack[j],     e1 = epack[j + 1], e2 = epack[j + 2], e3 = epack[j + 3];
        int2 e4 = epack[j + 4], e5 = epack[j + 5], e6 = epack[j + 6], e7 = epack[j + 7];
        float v0 = __half2float(Fprev[(size_t)e0.x * 64 + lane]);
        float v1 = __half2float(Fprev[(size_t)e1.x * 64 + lane]);
        float v2 = __half2float(Fprev[(size_t)e2.x * 64 + lane]);
        float v3 = __half2float(Fprev[(size_t)e3.x * 64 + lane]);
        float v4 = __half2float(Fprev[(size_t)e4.x * 64 + lane]);
        float v5 = __half2float(Fprev[(size_t)e5.x * 64 + lane]);
        float v6 = __half2float(Fprev[(size_t)e6.x * 64 + lane]);
        float v7 = __half2float(Fprev[(size_t)e7.x * 64 + lane]);
        acc = fmaf(v0, __int_as_float(e0.y), acc);
        acc = fmaf(v1, __int_as_float(e1.y), acc);
        acc = fmaf(v2, __int_as_float(e2.y), acc);
        acc = fmaf(v3, __int_as_float(e3.y), acc);
        acc = fmaf(v4, __int_as_float(e4.y), acc);
        acc = fmaf(v5, __int_as_float(e5.y), acc);
        acc = fmaf(v6, __int_as_float(e6.y), acc);
        acc = fmaf(v7, __int_as_float(e7.y), acc);
    }
    for (; j < end; ++j) {
        int2 e = epack[j];
        acc = fmaf(__half2float(Fprev[(size_t)e.x * 64 + lane]), __int_as_float(e.y), acc);
    }
    float self = __half2float(Fprev[(size_t)wid * 64 + lane]);
    Fnew[(size_t)wid * 64 + lane] = __float2half(self - acc * dinv[wid]);
}

// ---------------- final (MFMA): out = relu(A@B + bm1) @ Wm2 + bm2 ----------------
// ONE 16-row tile per wave (6252 waves; TLP). A = [L0|L1|L2|L3] fp16 contiguous;
// B pre-packed fragment order. D: col n = nt*16 + (l&15), row = (l>>4)*4 + reg.
__global__ __launch_bounds__(256) void final_mfma_kernel(
    const __half* __restrict__ L0h, const __half* __restrict__ Bpack,
    const float* __restrict__ Wm2, const float* __restrict__ bm1,
    const float* __restrict__ bm2, float* __restrict__ out)
{
    const size_t NH = (size_t)N_NODES * 64;
    int t = threadIdx.x;
    int wv = t >> 6;
    int lane = t & 63;
    int tile = blockIdx.x * 4 + wv;
    if (tile >= 6250) return;          // 6250 * 16 = 100000 exactly

    const f16x8* bp = (const f16x8*)Bpack;
    f16x8 b[4][8];
    #pragma unroll
    for (int s = 0; s < 8; ++s)
        #pragma unroll
        for (int nt = 0; nt < 4; ++nt)
            b[nt][s] = bp[(s * 4 + nt) * 64 + lane];

    float bm1v[4], w20[4], w21[4];
    #pragma unroll
    for (int nt = 0; nt < 4; ++nt) {
        int n = nt * 16 + (lane & 15);
        bm1v[nt] = bm1[n];
        w20[nt] = Wm2[n * 2 + 0];
        w21[nt] = Wm2[n * 2 + 1];
    }
    float bm20 = bm2[0], bm21 = bm2[1];

    int row0 = tile * 16;
    const __half* abase = L0h + (size_t)(row0 + (lane & 15)) * 64 + ((lane >> 4) << 3);
    f16x8 a[8];
    #pragma unroll
    for (int s = 0; s < 8; ++s)
        a[s] = *(const f16x8*)(abase + (size_t)(s >> 1) * NH + 32 * (s & 1));
    f32x4 acc[4];
    #pragma unroll
    for (int nt = 0; nt < 4; ++nt) acc[nt] = (f32x4){0.f, 0.f, 0.f, 0.f};
    #pragma unroll
    for (int s = 0; s < 8; ++s)
        #pragma unroll
        for (int nt = 0; nt < 4; ++nt)
            acc[nt] = __builtin_amdgcn_mfma_f32_16x16x32_f16(a[s], b[nt][s], acc[nt], 0, 0, 0);
    float o0[4], o1[4];
    #pragma unroll
    for (int reg = 0; reg < 4; ++reg) { o0[reg] = 0.f; o1[reg] = 0.f; }
    #pragma unroll
    for (int nt = 0; nt < 4; ++nt)
        #pragma unroll
        for (int reg = 0; reg < 4; ++reg) {
            float v = fmaxf(acc[nt][reg] + bm1v[nt], 0.f);
            o0[reg] = fmaf(v, w20[nt], o0[reg]);
            o1[reg] = fmaf(v, w21[nt], o1[reg]);
        }
    #pragma unroll
    for (int reg = 0; reg < 4; ++reg) {
        #pragma unroll
        for (int m = 8; m > 0; m >>= 1) {
            o0[reg] += __shfl_xor(o0[reg], m);
            o1[reg] += __shfl_xor(o1[reg], m);
        }
    }
    if ((lane & 15) == 0) {
        int rbase = row0 + (lane >> 4) * 4;
        #pragma unroll
        for (int reg = 0; reg < 4; ++reg) {
            out[(rbase + reg) * 2 + 0] = o0[reg] + bm20;
            out[(rbase + reg) * 2 + 1] = o1[reg] + bm21;
        }
    }
}

extern "C" void kernel_launch(void* const* d_in, const int* in_sizes, int n_in,
                              void* d_out, int out_size, void* d_ws, size_t ws_size,
                              hipStream_t stream)
{
    const float* feature = (const float*)d_in[0];
    const int*   src     = (const int*)d_in[1];
    const int*   dst     = (const int*)d_in[2];
    const float* W1      = (const float*)d_in[3];
    const float* b1      = (const float*)d_in[4];
    const float* W2      = (const float*)d_in[5];
    const float* b2      = (const float*)d_in[6];
    const float* thetas  = (const float*)d_in[7];
    const float* Wm1     = (const float*)d_in[8];
    const float* bm1     = (const float*)d_in[9];
    const float* Wm2     = (const float*)d_in[10];
    const float* bm2     = (const float*)d_in[11];
    float* out = (float*)d_out;

    const size_t NH = (size_t)N_NODES * H_FEATS;   // 6.4M elems
    const int NPAD = 100352;
    float*  dinv    = (float*)d_ws;                   // N
    int*    rowp    = (int*)(dinv + NPAD);            // N+1
    int*    blkcnt  = rowp + NPAD;                    // 512*500 (1 MB)
    int*    boff    = blkcnt + NBA * NBUK;            // 512*500 (1 MB)
    int*    buktot  = boff + NBA * NBUK;              // 500
    int*    bukbase = buktot + 512;                   // 500
    int2*   ebuck   = (int2*)(bukbase + 512);         // E int2 (12.8 MB)
    int2*   epack   = ebuck + N_EDGES;                // E int2 (12.8 MB)
    __half* Lh      = (__half*)(epack + N_EDGES);     // 4 x NH halfs (51.2 MB)
    __half* Bpack   = Lh + 4 * NH;                    // 16384 halfs
    __half* W1p     = Bpack + 16384;                  // 8192 halfs
    __half* W2p     = W1p + 8192;                     // 4096 halfs
    // total ws use ≈ 80 MB; no memsets (every array fully written before read)

    prep_kernel<<<112, 256, 0, stream>>>(thetas, Wm1, W1, W2, Bpack, W1p, W2p);
    trunk_mfma_kernel<<<1563, 256, 0, stream>>>(feature, W1p, b1, W2p, b2, Lh);  // -> L0h

    bucketA_kernel<<<NBA, 256, 0, stream>>>(dst, blkcnt);
    bucketB1_kernel<<<NBUK, 512, 0, stream>>>(blkcnt, boff, buktot);
    bucketB2_kernel<<<1, 512, 0, stream>>>(buktot, bukbase, rowp);
    bucketC_kernel<<<NBA, 256, 0, stream>>>(src, dst, boff, bukbase, ebuck);
    bucketD1_kernel<<<NBUK, 256, 0, stream>>>(ebuck, bukbase, buktot, rowp, dinv);
    bucketD2_kernel<<<NBUK, 256, 0, stream>>>(ebuck, bukbase, buktot, rowp, dinv, epack);

    for (int k = 1; k <= 3; ++k)
        gather_kernel<<<25000, 256, 0, stream>>>(Lh + (size_t)(k - 1) * NH, rowp, epack,
                                                 dinv, Lh + (size_t)k * NH);

    final_mfma_kernel<<<1563, 256, 0, stream>>>(Lh, Bpack, Wm2, bm1, bm2, out);
}

// Round 21
// 212.011 us; speedup vs baseline: 1.6923x; 1.1450x over previous
//
#include <hip/hip_runtime.h>
#include <hip/hip_fp16.h>
#include <math.h>

#define N_NODES 100000
#define N_EDGES 1600000
#define IN_FEATS 128
#define H_FEATS 64
#define NBUK 500          // buckets
#define BSZ 200           // nodes per bucket (500*200 = 100000)
#define NBA 512           // blocks for count/scatter
#define ACHUNK 3125       // 512*3125 = 1600000 exactly

typedef _Float16 f16x8 __attribute__((ext_vector_type(8)));
typedef float f32x4 __attribute__((ext_vector_type(4)));

// ---------------- A: per-block bucket histogram (LDS atomics only) ----------------
__global__ __launch_bounds__(256) void bucketA_kernel(const int* __restrict__ dst,
                                                      int* __restrict__ blkcnt) {
    __shared__ int cnt[NBUK];
    int t = threadIdx.x;
    for (int i = t; i < NBUK; i += 256) cnt[i] = 0;
    __syncthreads();
    int e0 = blockIdx.x * ACHUNK;
    for (int e = e0 + t; e < e0 + ACHUNK; e += 256)
        atomicAdd(&cnt[dst[e] / BSZ], 1);
    __syncthreads();
    for (int i = t; i < NBUK; i += 256)
        blkcnt[blockIdx.x * NBUK + i] = cnt[i];   // coalesced
}

// ---------------- B1: per-bucket exclusive scan over blocks + totals ----------------
__global__ __launch_bounds__(512) void bucketB1_kernel(const int* __restrict__ blkcnt,
                                                       int* __restrict__ boff,
                                                       int* __restrict__ buktot) {
    __shared__ int tmp[512];
    int b = blockIdx.x;      // bucket
    int t = threadIdx.x;     // block index
    int v = blkcnt[t * NBUK + b];
    tmp[t] = v;
    __syncthreads();
    #pragma unroll
    for (int off = 1; off < 512; off <<= 1) {
        int x = (t >= off) ? tmp[t - off] : 0;
        __syncthreads();
        tmp[t] += x;
        __syncthreads();
    }
    boff[t * NBUK + b] = tmp[t] - v;
    if (t == 511) buktot[b] = tmp[511];
}

// ---------------- B2: exclusive scan of bucket totals ----------------
__global__ __launch_bounds__(512) void bucketB2_kernel(const int* __restrict__ buktot,
                                                       int* __restrict__ bukbase,
                                                       int* __restrict__ rowp) {
    __shared__ int tmp[512];
    int t = threadIdx.x;
    int v = (t < NBUK) ? buktot[t] : 0;
    tmp[t] = v;
    __syncthreads();
    #pragma unroll
    for (int off = 1; off < 512; off <<= 1) {
        int x = (t >= off) ? tmp[t - off] : 0;
        __syncthreads();
        tmp[t] += x;
        __syncthreads();
    }
    if (t < NBUK) bukbase[t] = tmp[t] - v;
    if (t == 0) rowp[N_NODES] = N_EDGES;
}

// ---------------- C: scatter packed edges into bucket-sorted ebuck ----------------
// pack = (src << 8) | (dst % BSZ): src < 2^17, local dst < 2^8 -> 25 bits.
__global__ __launch_bounds__(256) void bucketC_kernel(const int* __restrict__ src,
                                                      const int* __restrict__ dst,
                                                      const int* __restrict__ boff,
                                                      const int* __restrict__ bukbase,
                                                      int* __restrict__ ebuck) {
    __shared__ int sbase[NBUK];
    __shared__ int cur[NBUK];
    int t = threadIdx.x;
    for (int i = t; i < NBUK; i += 256) {
        sbase[i] = bukbase[i] + boff[blockIdx.x * NBUK + i];
        cur[i] = 0;
    }
    __syncthreads();
    int e0 = blockIdx.x * ACHUNK;
    for (int e = e0 + t; e < e0 + ACHUNK; e += 256) {
        int d = dst[e];
        int b = d / BSZ;
        int r = atomicAdd(&cur[b], 1);
        ebuck[sbase[b] + r] = (src[e] << 8) | (d - b * BSZ);
    }
}

// ---------------- D1: per-bucket degrees -> rowp (global slot base) + dinv ----------
__global__ __launch_bounds__(256) void bucketD1_kernel(const int* __restrict__ ebuck,
                                                       const int* __restrict__ bukbase,
                                                       const int* __restrict__ buktot,
                                                       int* __restrict__ rowp,
                                                       float* __restrict__ dinv) {
    __shared__ int deg[BSZ];
    __shared__ int tmp[256];
    int t = threadIdx.x;
    int buk = blockIdx.x;
    int nlo = buk * BSZ;
    int base = bukbase[buk];
    int cnt = buktot[buk];
    for (int i = t; i < BSZ; i += 256) deg[i] = 0;
    __syncthreads();
    for (int k = t; k < cnt; k += 256)
        atomicAdd(&deg[ebuck[base + k] & 255], 1);
    __syncthreads();
    int v = (t < BSZ) ? deg[t] : 0;
    tmp[t] = v;
    __syncthreads();
    #pragma unroll
    for (int off = 1; off < 256; off <<= 1) {
        int x = (t >= off) ? tmp[t - off] : 0;
        __syncthreads();
        tmp[t] += x;
        __syncthreads();
    }
    if (t < BSZ) {
        rowp[nlo + t] = base + tmp[t] - v;
        dinv[nlo + t] = rsqrtf(fmaxf((float)v, 1.0f));
    }
}

// ---------------- D2: rank packed ebuck (L2/L3-hot) -> epack (src, bits(dinv[src]))
__global__ __launch_bounds__(256) void bucketD2_kernel(const int* __restrict__ ebuck,
                                                       const int* __restrict__ bukbase,
                                                       const int* __restrict__ buktot,
                                                       const int* __restrict__ rowp,
                                                       const float* __restrict__ dinv,
                                                       int2* __restrict__ epack) {
    __shared__ int rp[BSZ];
    __shared__ int cur2[BSZ];
    int t = threadIdx.x;
    int buk = blockIdx.x;
    int nlo = buk * BSZ;
    int base = bukbase[buk];
    int cnt = buktot[buk];
    for (int i = t; i < BSZ; i += 256) { rp[i] = rowp[nlo + i]; cur2[i] = 0; }
    __syncthreads();
    for (int k = t; k < cnt; k += 256) {
        int p = ebuck[base + k];
        int ld = p & 255;
        int s = p >> 8;
        int r = atomicAdd(&cur2[ld], 1);
        epack[rp[ld] + r] = make_int2(s, __float_as_int(dinv[s]));
    }
}

// ---------------- prep: pack Weff/W1/W2 into fp16 MFMA B-fragment order ----------------
// Fragment (s,nt): lane l, elem j holds B[k = 32s + (l>>4)*8 + j][n = nt*16 + (l&15)]
__global__ __launch_bounds__(256) void prep_kernel(const float* __restrict__ thetas,
                                                   const float* __restrict__ Wm1,
                                                   const float* __restrict__ W1,
                                                   const float* __restrict__ W2,
                                                   __half* __restrict__ Bpack,
                                                   __half* __restrict__ W1p,
                                                   __half* __restrict__ W2p) {
    int u = blockIdx.x * 256 + threadIdx.x;
    if (u < 16384) {
        int j = u & 7, lane = (u >> 3) & 63, frag = u >> 9;
        int nt = frag & 3, s = frag >> 2;
        int k = 32 * s + ((lane >> 4) << 3) + j;
        int q = k >> 6, f = k & 63;
        int n = nt * 16 + (lane & 15);
        float acc = 0.f;
        #pragma unroll
        for (int c = 0; c < 3; ++c)
            acc = fmaf(thetas[c * 4 + q], Wm1[(c * 64 + f) * 64 + n], acc);
        Bpack[u] = __float2half(acc);
    } else if (u < 16384 + 8192) {
        int v = u - 16384;
        int j = v & 7, lane = (v >> 3) & 63, frag = v >> 9;   // frag 0..15
        int nt = frag & 3, s = frag >> 2;
        int k = 32 * s + ((lane >> 4) << 3) + j;              // 0..127
        int n = nt * 16 + (lane & 15);
        W1p[v] = __float2half(W1[k * 64 + n]);
    } else if (u < 16384 + 8192 + 4096) {
        int v = u - 24576;
        int j = v & 7, lane = (v >> 3) & 63, frag = v >> 9;   // frag 0..7
        int nt = frag & 3, s2 = frag >> 2;
        int k = 32 * s2 + ((lane >> 4) << 3) + j;             // 0..63
        int n = nt * 16 + (lane & 15);
        W2p[v] = __float2half(W2[k * 64 + n]);
    }
}

// ---------------- trunk (MFMA): H = fp16(relu(relu(X@W1+b1)@W2+b2)) ----------------
// ONE 16-row tile per wave. Layouts identical to final_mfma (verified).
// Swizzle: byte ^= (row&7)<<4.
__global__ __launch_bounds__(256) void trunk_mfma_kernel(
    const float* __restrict__ X, const __half* __restrict__ W1p, const float* __restrict__ b1,
    const __half* __restrict__ W2p, const float* __restrict__ b2, __half* __restrict__ H)
{
    __shared__ __half hl[4][1024];   // 2 KB per wave
    int t = threadIdx.x;
    int wv = t >> 6, lane = t & 63;
    int r_lo = lane & 15;            // A-frag row / D col
    int g = lane >> 4;               // k-group / D row group
    char* myl = (char*)hl[wv];

    int tile = blockIdx.x * 4 + wv;
    if (tile >= 6250) return;        // 6250*16 = 100000 exactly; no barriers below

    const f16x8* w1f = (const f16x8*)W1p;
    const f16x8* w2f = (const f16x8*)W2p;
    f16x8 w1b[16], w2b[8];
    #pragma unroll
    for (int f = 0; f < 16; ++f) w1b[f] = w1f[f * 64 + lane];
    #pragma unroll
    for (int f = 0; f < 8; ++f)  w2b[f] = w2f[f * 64 + lane];
    float b1v[4], b2v[4];
    #pragma unroll
    for (int nt = 0; nt < 4; ++nt) {
        b1v[nt] = b1[nt * 16 + r_lo];
        b2v[nt] = b2[nt * 16 + r_lo];
    }

    int row0 = tile * 16;
    const float* xb = X + (size_t)(row0 + r_lo) * IN_FEATS + g * 8;
    f16x8 a1[4];
    #pragma unroll
    for (int s = 0; s < 4; ++s) {
        float4 f0 = *(const float4*)(xb + 32 * s);
        float4 f1 = *(const float4*)(xb + 32 * s + 4);
        f16x8 a;
        a[0] = (_Float16)f0.x; a[1] = (_Float16)f0.y;
        a[2] = (_Float16)f0.z; a[3] = (_Float16)f0.w;
        a[4] = (_Float16)f1.x; a[5] = (_Float16)f1.y;
        a[6] = (_Float16)f1.z; a[7] = (_Float16)f1.w;
        a1[s] = a;
    }
    f32x4 acc1[4];
    #pragma unroll
    for (int nt = 0; nt < 4; ++nt) acc1[nt] = (f32x4){0.f, 0.f, 0.f, 0.f};
    #pragma unroll
    for (int s = 0; s < 4; ++s)
        #pragma unroll
        for (int nt = 0; nt < 4; ++nt)
            acc1[nt] = __builtin_amdgcn_mfma_f32_16x16x32_f16(a1[s], w1b[s * 4 + nt], acc1[nt], 0, 0, 0);
    #pragma unroll
    for (int nt = 0; nt < 4; ++nt)
        #pragma unroll
        for (int reg = 0; reg < 4; ++reg) {
            int r = g * 4 + reg;
            int c = nt * 16 + r_lo;
            int byte = (r * 128 + c * 2) ^ ((r & 7) << 4);
            *(__half*)(myl + byte) = __float2half(fmaxf(acc1[nt][reg] + b1v[nt], 0.f));
        }
    f16x8 a2[2];
    #pragma unroll
    for (int s2 = 0; s2 < 2; ++s2) {
        int byte = (r_lo * 128 + 64 * s2 + g * 16) ^ ((r_lo & 7) << 4);
        a2[s2] = *(const f16x8*)(myl + byte);
    }
    f32x4 acc2[4];
    #pragma unroll
    for (int nt = 0; nt < 4; ++nt) acc2[nt] = (f32x4){0.f, 0.f, 0.f, 0.f};
    #pragma unroll
    for (int s2 = 0; s2 < 2; ++s2)
        #pragma unroll
        for (int nt = 0; nt < 4; ++nt)
            acc2[nt] = __builtin_amdgcn_mfma_f32_16x16x32_f16(a2[s2], w2b[s2 * 4 + nt], acc2[nt], 0, 0, 0);
    #pragma unroll
    for (int nt = 0; nt < 4; ++nt)
        #pragma unroll
        for (int reg = 0; reg < 4; ++reg) {
            int r = g * 4 + reg;
            int c = nt * 16 + r_lo;
            int byte = (r * 128 + c * 2) ^ ((r & 7) << 4);
            *(__half*)(myl + byte) = __float2half(fmaxf(acc2[nt][reg] + b2v[nt], 0.f));
        }
    #pragma unroll
    for (int h2 = 0; h2 < 2; ++h2) {
        int R = (lane >> 3) + 8 * h2;    // row 0..15
        int w = lane & 7;                // 16B slot
        int byte = (R * 128 + 16 * (w ^ (R & 7)));
        f16x8 hv = *(const f16x8*)(myl + byte);
        *(f16x8*)(H + (size_t)(row0 + R) * 64 + w * 8) = hv;
    }
}

// ---------------- gather pass: Fnew[n] = Fprev[n] - dinv[n]*sum_e w_e*Fprev[s_e]
// half tables (128B row per edge), fp32 accumulate; one wave per node.
// Unroll ladder 16/8/4/1: up to 16 row-loads in flight per wave.
__global__ __launch_bounds__(256) void gather_kernel(
    const __half* __restrict__ Fprev, const int* __restrict__ rowp,
    const int2* __restrict__ epack, const float* __restrict__ dinv,
    __half* __restrict__ Fnew)
{
    int wv = __builtin_amdgcn_readfirstlane(threadIdx.x >> 6);
    int wid = blockIdx.x * 4 + wv;   // node id (uniform)
    int lane = threadIdx.x & 63;
    int beg = rowp[wid], end = rowp[wid + 1];
    float acc = 0.0f;
    int j = beg;
    for (; j + 15 < end; j += 16) {
        int2 e[16];
        #pragma unroll
        for (int q = 0; q < 16; ++q) e[q] = epack[j + q];
        float v[16];
        #pragma unroll
        for (int q = 0; q < 16; ++q)
            v[q] = __half2float(Fprev[(size_t)e[q].x * 64 + lane]);
        #pragma unroll
        for (int q = 0; q < 16; ++q)
            acc = fmaf(v[q], __int_as_float(e[q].y), acc);
    }
    for (; j + 7 < end; j += 8) {
        int2 e[8];
        #pragma unroll
        for (int q = 0; q < 8; ++q) e[q] = epack[j + q];
        float v[8];
        #pragma unroll
        for (int q = 0; q < 8; ++q)
            v[q] = __half2float(Fprev[(size_t)e[q].x * 64 + lane]);
        #pragma unroll
        for (int q = 0; q < 8; ++q)
            acc = fmaf(v[q], __int_as_float(e[q].y), acc);
    }
    for (; j + 3 < end; j += 4) {
        int2 e[4];
        #pragma unroll
        for (int q = 0; q < 4; ++q) e[q] = epack[j + q];
        float v[4];
        #pragma unroll
        for (int q = 0; q < 4; ++q)
            v[q] = __half2float(Fprev[(size_t)e[q].x * 64 + lane]);
        #pragma unroll
        for (int q = 0; q < 4; ++q)
            acc = fmaf(v[q], __int_as_float(e[q].y), acc);
    }
    for (; j < end; ++j) {
        int2 e = epack[j];
        acc = fmaf(__half2float(Fprev[(size_t)e.x * 64 + lane]), __int_as_float(e.y), acc);
    }
    float self = __half2float(Fprev[(size_t)wid * 64 + lane]);
    Fnew[(size_t)wid * 64 + lane] = __float2half(self - acc * dinv[wid]);
}

// ---------------- final (MFMA): out = relu(A@B + bm1) @ Wm2 + bm2 ----------------
// ONE 16-row tile per wave. A = [L0|L1|L2|L3] fp16 contiguous; B pre-packed
// fragment order. D: col n = nt*16 + (l&15), row = (l>>4)*4 + reg.
__global__ __launch_bounds__(256) void final_mfma_kernel(
    const __half* __restrict__ L0h, const __half* __restrict__ Bpack,
    const float* __restrict__ Wm2, const float* __restrict__ bm1,
    const float* __restrict__ bm2, float* __restrict__ out)
{
    const size_t NH = (size_t)N_NODES * 64;
    int t = threadIdx.x;
    int wv = t >> 6;
    int lane = t & 63;
    int tile = blockIdx.x * 4 + wv;
    if (tile >= 6250) return;          // 6250 * 16 = 100000 exactly

    const f16x8* bp = (const f16x8*)Bpack;
    f16x8 b[4][8];
    #pragma unroll
    for (int s = 0; s < 8; ++s)
        #pragma unroll
        for (int nt = 0; nt < 4; ++nt)
            b[nt][s] = bp[(s * 4 + nt) * 64 + lane];

    float bm1v[4], w20[4], w21[4];
    #pragma unroll
    for (int nt = 0; nt < 4; ++nt) {
        int n = nt * 16 + (lane & 15);
        bm1v[nt] = bm1[n];
        w20[nt] = Wm2[n * 2 + 0];
        w21[nt] = Wm2[n * 2 + 1];
    }
    float bm20 = bm2[0], bm21 = bm2[1];

    int row0 = tile * 16;
    const __half* abase = L0h + (size_t)(row0 + (lane & 15)) * 64 + ((lane >> 4) << 3);
    f16x8 a[8];
    #pragma unroll
    for (int s = 0; s < 8; ++s)
        a[s] = *(const f16x8*)(abase + (size_t)(s >> 1) * NH + 32 * (s & 1));
    f32x4 acc[4];
    #pragma unroll
    for (int nt = 0; nt < 4; ++nt) acc[nt] = (f32x4){0.f, 0.f, 0.f, 0.f};
    #pragma unroll
    for (int s = 0; s < 8; ++s)
        #pragma unroll
        for (int nt = 0; nt < 4; ++nt)
            acc[nt] = __builtin_amdgcn_mfma_f32_16x16x32_f16(a[s], b[nt][s], acc[nt], 0, 0, 0);
    float o0[4], o1[4];
    #pragma unroll
    for (int reg = 0; reg < 4; ++reg) { o0[reg] = 0.f; o1[reg] = 0.f; }
    #pragma unroll
    for (int nt = 0; nt < 4; ++nt)
        #pragma unroll
        for (int reg = 0; reg < 4; ++reg) {
            float v = fmaxf(acc[nt][reg] + bm1v[nt], 0.f);
            o0[reg] = fmaf(v, w20[nt], o0[reg]);
            o1[reg] = fmaf(v, w21[nt], o1[reg]);
        }
    #pragma unroll
    for (int reg = 0; reg < 4; ++reg) {
        #pragma unroll
        for (int m = 8; m > 0; m >>= 1) {
            o0[reg] += __shfl_xor(o0[reg], m);
            o1[reg] += __shfl_xor(o1[reg], m);
        }
    }
    if ((lane & 15) == 0) {
        int rbase = row0 + (lane >> 4) * 4;
        #pragma unroll
        for (int reg = 0; reg < 4; ++reg) {
            out[(rbase + reg) * 2 + 0] = o0[reg] + bm20;
            out[(rbase + reg) * 2 + 1] = o1[reg] + bm21;
        }
    }
}

extern "C" void kernel_launch(void* const* d_in, const int* in_sizes, int n_in,
                              void* d_out, int out_size, void* d_ws, size_t ws_size,
                              hipStream_t stream)
{
    const float* feature = (const float*)d_in[0];
    const int*   src     = (const int*)d_in[1];
    const int*   dst     = (const int*)d_in[2];
    const float* W1      = (const float*)d_in[3];
    const float* b1      = (const float*)d_in[4];
    const float* W2      = (const float*)d_in[5];
    const float* b2      = (const float*)d_in[6];
    const float* thetas  = (const float*)d_in[7];
    const float* Wm1     = (const float*)d_in[8];
    const float* bm1     = (const float*)d_in[9];
    const float* Wm2     = (const float*)d_in[10];
    const float* bm2     = (const float*)d_in[11];
    float* out = (float*)d_out;

    const size_t NH = (size_t)N_NODES * H_FEATS;   // 6.4M elems
    const int NPAD = 100352;
    float*  dinv    = (float*)d_ws;                   // N
    int*    rowp    = (int*)(dinv + NPAD);            // N+1
    int*    blkcnt  = rowp + NPAD;                    // 512*500 (1 MB)
    int*    boff    = blkcnt + NBA * NBUK;            // 512*500 (1 MB)
    int*    buktot  = boff + NBA * NBUK;              // 500
    int*    bukbase = buktot + 512;                   // 500
    int*    ebuck   = bukbase + 512;                  // E packed int (6.4 MB)
    int2*   epack   = (int2*)(ebuck + N_EDGES);       // E int2 (12.8 MB)
    __half* Lh      = (__half*)(epack + N_EDGES);     // 4 x NH halfs (51.2 MB)
    __half* Bpack   = Lh + 4 * NH;                    // 16384 halfs
    __half* W1p     = Bpack + 16384;                  // 8192 halfs
    __half* W2p     = W1p + 8192;                     // 4096 halfs
    // total ws use ≈ 74 MB; no memsets (every array fully written before read)

    prep_kernel<<<112, 256, 0, stream>>>(thetas, Wm1, W1, W2, Bpack, W1p, W2p);
    trunk_mfma_kernel<<<1563, 256, 0, stream>>>(feature, W1p, b1, W2p, b2, Lh);  // -> L0h

    bucketA_kernel<<<NBA, 256, 0, stream>>>(dst, blkcnt);
    bucketB1_kernel<<<NBUK, 512, 0, stream>>>(blkcnt, boff, buktot);
    bucketB2_kernel<<<1, 512, 0, stream>>>(buktot, bukbase, rowp);
    bucketC_kernel<<<NBA, 256, 0, stream>>>(src, dst, boff, bukbase, ebuck);
    bucketD1_kernel<<<NBUK, 256, 0, stream>>>(ebuck, bukbase, buktot, rowp, dinv);
    bucketD2_kernel<<<NBUK, 256, 0, stream>>>(ebuck, bukbase, buktot, rowp, dinv, epack);

    for (int k = 1; k <= 3; ++k)
        gather_kernel<<<25000, 256, 0, stream>>>(Lh + (size_t)(k - 1) * NH, rowp, epack,
                                                 dinv, Lh + (size_t)k * NH);

    final_mfma_kernel<<<1563, 256, 0, stream>>>(Lh, Bpack, Wm2, bm1, bm2, out);
}